// Round 1
// baseline (180.525 us; speedup 1.0000x reference)
//
#include <hip/hip_runtime.h>
#include <hip/hip_bf16.h>

// Shapes (fixed by the reference): B=4, S=2048, D=2048, R=2048, LR=16
#define SCALE_V 1.0f

typedef __bf16 bf16v8 __attribute__((ext_vector_type(8)));
typedef float f32v4 __attribute__((ext_vector_type(4)));

typedef const __attribute__((address_space(1))) void* gas_t;
typedef __attribute__((address_space(3))) void* las_t;
#define ASYNC_COPY16(g, l) \
    __builtin_amdgcn_global_load_lds((gas_t)(g), (las_t)(l), 16, 0, 0)

// ---------------------------------------------------------------------------
// Kernel 1: weight fp32 -> bf16   (4,194,304 elems, 8 per thread)
// ---------------------------------------------------------------------------
__global__ __launch_bounds__(256) void convert_w_kernel(
    const float* __restrict__ w, __bf16* __restrict__ wb) {
    const int i = (blockIdx.x * 256 + threadIdx.x) * 8;
    float4 x0 = *(const float4*)(w + i);
    float4 x1 = *(const float4*)(w + i + 4);
    bf16v8 v;
    v[0] = (__bf16)x0.x; v[1] = (__bf16)x0.y; v[2] = (__bf16)x0.z; v[3] = (__bf16)x0.w;
    v[4] = (__bf16)x1.x; v[5] = (__bf16)x1.y; v[6] = (__bf16)x1.z; v[7] = (__bf16)x1.w;
    *(bf16v8*)(wb + i) = v;
}

// ---------------------------------------------------------------------------
// Kernel 2: Gram partials  G[b] = L_b @ L_b^T   (16x16, contracted over R=2048)
// grid (8 r-chunks, 4 batches), thread = (k,j) pair
// ---------------------------------------------------------------------------
__global__ __launch_bounds__(256) void gram_part_kernel(
    const float* __restrict__ lleft, float* __restrict__ gpart) {
    const int b = blockIdx.y, c = blockIdx.x;
    const int k = threadIdx.x >> 4, j = threadIdx.x & 15;
    const float* pk = lleft + ((size_t)b * 16 + k) * 2048 + c * 256;
    const float* pj = lleft + ((size_t)b * 16 + j) * 2048 + c * 256;
    float s = 0.f;
    #pragma unroll 4
    for (int r = 0; r < 256; r += 4) {
        float4 a = *(const float4*)(pk + r);
        float4 d = *(const float4*)(pj + r);
        s += a.x * d.x + a.y * d.y + a.z * d.z + a.w * d.w;
    }
    gpart[((size_t)b * 8 + c) * 256 + threadIdx.x] = s;
}

// ---------------------------------------------------------------------------
// Kernel 3: fused input fp32->bf16 + t = input @ lora_right  ([8192,16])
// one block = 4 token rows; thread handles 8 consecutive d's
// ---------------------------------------------------------------------------
__global__ __launch_bounds__(256) void lora_t_kernel(
    const float* __restrict__ inp, const float* __restrict__ lright,
    __bf16* __restrict__ abf, float* __restrict__ tout) {
    const int tid = threadIdx.x;
    const int row0 = blockIdx.x * 4;
    const int b = row0 >> 11;
    const float* rb = lright + (size_t)b * 2048 * 16;

    float x[4][8];
    #pragma unroll
    for (int rr = 0; rr < 4; ++rr) {
        const float* p = inp + (size_t)(row0 + rr) * 2048 + tid * 8;
        float4 a0 = *(const float4*)p;
        float4 a1 = *(const float4*)(p + 4);
        x[rr][0] = a0.x; x[rr][1] = a0.y; x[rr][2] = a0.z; x[rr][3] = a0.w;
        x[rr][4] = a1.x; x[rr][5] = a1.y; x[rr][6] = a1.z; x[rr][7] = a1.w;
        bf16v8 v;
        #pragma unroll
        for (int i = 0; i < 8; ++i) v[i] = (__bf16)x[rr][i];
        *(bf16v8*)(abf + (size_t)(row0 + rr) * 2048 + tid * 8) = v;
    }

    float acc[4][16];
    #pragma unroll
    for (int rr = 0; rr < 4; ++rr)
        #pragma unroll
        for (int k = 0; k < 16; ++k) acc[rr][k] = 0.f;

    #pragma unroll
    for (int i = 0; i < 8; ++i) {
        const int d = tid * 8 + i;
        const float* rrow = rb + (size_t)d * 16;
        float4 r0 = *(const float4*)(rrow);
        float4 r1 = *(const float4*)(rrow + 4);
        float4 r2 = *(const float4*)(rrow + 8);
        float4 r3 = *(const float4*)(rrow + 12);
        float rv[16] = {r0.x, r0.y, r0.z, r0.w, r1.x, r1.y, r1.z, r1.w,
                        r2.x, r2.y, r2.z, r2.w, r3.x, r3.y, r3.z, r3.w};
        #pragma unroll
        for (int rr = 0; rr < 4; ++rr)
            #pragma unroll
            for (int k = 0; k < 16; ++k) acc[rr][k] += x[rr][i] * rv[k];
    }

    __shared__ float sm[4096];
    for (int rr = 0; rr < 4; ++rr) {
        #pragma unroll
        for (int k = 0; k < 16; ++k) sm[tid * 16 + k] = acc[rr][k];
        __syncthreads();
        if (tid < 128) {
            #pragma unroll
            for (int k = 0; k < 16; ++k)
                sm[tid * 16 + k] += sm[(tid + 128) * 16 + k];
        }
        __syncthreads();
        if (tid < 32) {
            #pragma unroll
            for (int k = 0; k < 16; ++k)
                sm[tid * 16 + k] += sm[(tid + 32) * 16 + k] +
                                    sm[(tid + 64) * 16 + k] +
                                    sm[(tid + 96) * 16 + k];
        }
        __syncthreads();
        if (tid < 16) {
            float s = 0.f;
            #pragma unroll
            for (int i = 0; i < 32; ++i) s += sm[i * 16 + tid];
            tout[(size_t)(row0 + rr) * 16 + tid] = s;
        }
        __syncthreads();
    }
}

// ---------------------------------------------------------------------------
// Kernel 4: fold Gram partials; t' = SCALE * t * rsqrt(t^T G t)  (in place)
// one thread per token; 32 blocks x 256
// ---------------------------------------------------------------------------
__global__ __launch_bounds__(256) void norm_kernel(
    const float* __restrict__ gpart, float* __restrict__ t) {
    __shared__ float gs[256];
    const int tid = threadIdx.x;
    const int tok0 = blockIdx.x * 256;
    const int b = tok0 >> 11;
    float g = 0.f;
    #pragma unroll
    for (int c = 0; c < 8; ++c) g += gpart[((size_t)b * 8 + c) * 256 + tid];
    gs[tid] = g;
    __syncthreads();

    const int tok = tok0 + tid;
    float* tp = t + (size_t)tok * 16;
    float tv[16];
    {
        float4 a0 = *(const float4*)(tp);
        float4 a1 = *(const float4*)(tp + 4);
        float4 a2 = *(const float4*)(tp + 8);
        float4 a3 = *(const float4*)(tp + 12);
        tv[0]=a0.x; tv[1]=a0.y; tv[2]=a0.z; tv[3]=a0.w;
        tv[4]=a1.x; tv[5]=a1.y; tv[6]=a1.z; tv[7]=a1.w;
        tv[8]=a2.x; tv[9]=a2.y; tv[10]=a2.z; tv[11]=a2.w;
        tv[12]=a3.x; tv[13]=a3.y; tv[14]=a3.z; tv[15]=a3.w;
    }
    float q = 0.f;
    #pragma unroll
    for (int k = 0; k < 16; ++k) {
        float s = 0.f;
        #pragma unroll
        for (int j = 0; j < 16; ++j) s += gs[k * 16 + j] * tv[j];
        q += tv[k] * s;
    }
    const float r = SCALE_V * rsqrtf(q);
    float4 o;
    o.x = tv[0]*r;  o.y = tv[1]*r;  o.z = tv[2]*r;  o.w = tv[3]*r;  *(float4*)(tp)      = o;
    o.x = tv[4]*r;  o.y = tv[5]*r;  o.z = tv[6]*r;  o.w = tv[7]*r;  *(float4*)(tp + 4)  = o;
    o.x = tv[8]*r;  o.y = tv[9]*r;  o.z = tv[10]*r; o.w = tv[11]*r; *(float4*)(tp + 8)  = o;
    o.x = tv[12]*r; o.y = tv[13]*r; o.z = tv[14]*r; o.w = tv[15]*r; *(float4*)(tp + 12) = o;
}

// ---------------------------------------------------------------------------
// Kernel 5: C = Abf @ Wbf^T (+ bias + LoRA K-extension), m97-style 128x128x32
// grid (16 col-tiles, 64 row-tiles) x 256 threads (4 waves, 2x2)
// ---------------------------------------------------------------------------
__global__ __launch_bounds__(256) void gemm_ep_kernel(
    const __bf16* __restrict__ abf, const __bf16* __restrict__ wbf,
    const float* __restrict__ bias, const float* __restrict__ tpr,
    const float* __restrict__ lleft, float* __restrict__ out) {
    __shared__ __attribute__((aligned(16))) __bf16 As[128][32];
    __shared__ __attribute__((aligned(16))) __bf16 Bs[128][32];

    const int tid = threadIdx.x;
    const int row0 = blockIdx.y * 128;
    const int col0 = blockIdx.x * 128;
    const size_t K = 2048;

    // staging sources: chunk c = i*256 + tid -> row c/4, cols (c%4)*8..+7
    const __bf16* ag0 = abf + (size_t)(row0 + (tid >> 2)) * K + (tid & 3) * 8;
    const __bf16* ag1 = ag0 + 64 * K;
    const __bf16* bg0 = wbf + (size_t)(col0 + (tid >> 2)) * K + (tid & 3) * 8;
    const __bf16* bg1 = bg0 + 64 * K;
    char* lA0 = ((char*)&As[0][0]) + tid * 16;
    char* lA1 = lA0 + 4096;
    char* lB0 = ((char*)&Bs[0][0]) + tid * 16;
    char* lB1 = lB0 + 4096;

    const int wid = tid >> 6, lane = tid & 63;
    const int wm = (wid >> 1) * 64, wn = (wid & 1) * 64;
    const int fr = lane & 15, fk = (lane >> 4) * 8;
    const __bf16* aptr = &As[wm + fr][fk];
    const __bf16* bptr = &Bs[wn + fr][fk];

    f32v4 acc[4][4];
    #pragma unroll
    for (int m = 0; m < 4; ++m)
        #pragma unroll
        for (int n = 0; n < 4; ++n) {
            acc[m][n][0] = 0.f; acc[m][n][1] = 0.f;
            acc[m][n][2] = 0.f; acc[m][n][3] = 0.f;
        }

    for (int k0 = 0; k0 < 2048; k0 += 32) {
        ASYNC_COPY16(ag0 + k0, lA0);
        ASYNC_COPY16(ag1 + k0, lA1);
        ASYNC_COPY16(bg0 + k0, lB0);
        ASYNC_COPY16(bg1 + k0, lB1);
        __syncthreads();
        bf16v8 af[4], bf[4];
        #pragma unroll
        for (int m = 0; m < 4; ++m) af[m] = *(const bf16v8*)(aptr + m * 512);
        #pragma unroll
        for (int n = 0; n < 4; ++n) bf[n] = *(const bf16v8*)(bptr + n * 512);
        #pragma unroll
        for (int m = 0; m < 4; ++m)
            #pragma unroll
            for (int n = 0; n < 4; ++n)
                acc[m][n] = __builtin_amdgcn_mfma_f32_16x16x32_bf16(
                    af[m], bf[n], acc[m][n], 0, 0, 0);
        __syncthreads();
    }

    // ---- LoRA term as one zero-padded K=32 MFMA iteration ----
    {
        const int r = tid >> 1;
        const int h = (tid & 1) * 8;
        bf16v8 zv;
        #pragma unroll
        for (int i = 0; i < 8; ++i) zv[i] = (__bf16)0.f;

        const float* tp = tpr + (size_t)(row0 + r) * 16 + h;
        float4 t0 = *(const float4*)tp;
        float4 t1 = *(const float4*)(tp + 4);
        bf16v8 tv;
        tv[0]=(__bf16)t0.x; tv[1]=(__bf16)t0.y; tv[2]=(__bf16)t0.z; tv[3]=(__bf16)t0.w;
        tv[4]=(__bf16)t1.x; tv[5]=(__bf16)t1.y; tv[6]=(__bf16)t1.z; tv[7]=(__bf16)t1.w;
        *(bf16v8*)&As[r][h] = tv;
        *(bf16v8*)&As[r][h + 16] = zv;

        const int bb = row0 >> 11;
        const float* lp = lleft + ((size_t)bb * 16 + h) * 2048 + (col0 + r);
        bf16v8 lv;
        #pragma unroll
        for (int i = 0; i < 8; ++i) lv[i] = (__bf16)lp[(size_t)i * 2048];
        *(bf16v8*)&Bs[r][h] = lv;
        *(bf16v8*)&Bs[r][h + 16] = zv;
    }
    __syncthreads();
    {
        bf16v8 af[4], bf[4];
        #pragma unroll
        for (int m = 0; m < 4; ++m) af[m] = *(const bf16v8*)(aptr + m * 512);
        #pragma unroll
        for (int n = 0; n < 4; ++n) bf[n] = *(const bf16v8*)(bptr + n * 512);
        #pragma unroll
        for (int m = 0; m < 4; ++m)
            #pragma unroll
            for (int n = 0; n < 4; ++n)
                acc[m][n] = __builtin_amdgcn_mfma_f32_16x16x32_bf16(
                    af[m], bf[n], acc[m][n], 0, 0, 0);
    }

    // ---- writeout: C[row][col] = acc + bias[col] ----
    #pragma unroll
    for (int n = 0; n < 4; ++n) {
        const int gc = col0 + wn + n * 16 + fr;
        const float bv = bias[gc];
        #pragma unroll
        for (int m = 0; m < 4; ++m) {
            #pragma unroll
            for (int j = 0; j < 4; ++j) {
                const int gr = row0 + wm + m * 16 + (lane >> 4) * 4 + j;
                out[(size_t)gr * 2048 + gc] = acc[m][n][j] + bv;
            }
        }
    }
}

// ---------------------------------------------------------------------------
extern "C" void kernel_launch(void* const* d_in, const int* in_sizes, int n_in,
                              void* d_out, int out_size, void* d_ws, size_t ws_size,
                              hipStream_t stream) {
    const float* inp  = (const float*)d_in[0];   // [4,2048,2048]
    const float* wgt  = (const float*)d_in[1];   // [2048,2048]
    const float* bias = (const float*)d_in[2];   // [2048]
    const float* lrt  = (const float*)d_in[3];   // [4,2048,16]
    const float* llf  = (const float*)d_in[4];   // [4,16,2048]
    float* out = (float*)d_out;                  // [4,2048,2048]

    char* ws = (char*)d_ws;
    __bf16* abf  = (__bf16*)ws;                    // 33,554,432 B
    __bf16* wbf  = (__bf16*)(ws + 33554432);       //  8,388,608 B
    float*  tbuf = (float*)(ws + 41943040);        //    524,288 B
    float*  gprt = (float*)(ws + 42467328);        //     32,768 B

    convert_w_kernel<<<2048, 256, 0, stream>>>(wgt, wbf);
    gram_part_kernel<<<dim3(8, 4), 256, 0, stream>>>(llf, gprt);
    lora_t_kernel<<<2048, 256, 0, stream>>>(inp, lrt, abf, tbuf);
    norm_kernel<<<32, 256, 0, stream>>>(gprt, tbuf);
    gemm_ep_kernel<<<dim3(16, 64), 256, 0, stream>>>(abf, wbf, bias, tbuf, llf, out);
}

// Round 2
// 133.241 us; speedup vs baseline: 1.3549x; 1.3549x over previous
//
#include <hip/hip_runtime.h>
#include <hip/hip_bf16.h>

// Shapes fixed by reference: B=4, S=2048, D=K=2048, R=N=2048, LR=16, M=B*S=8192
#define SCALE_V 1.0f

typedef __bf16 bf16v8 __attribute__((ext_vector_type(8)));
typedef float f32v4 __attribute__((ext_vector_type(4)));

typedef const __attribute__((address_space(1))) void* gas_t;
typedef __attribute__((address_space(3))) void* las_t;
#define ASYNC_COPY16(g, l) \
    __builtin_amdgcn_global_load_lds((gas_t)(g), (las_t)(l), 16, 0, 0)
#define FENCE() asm volatile("" ::: "memory")
#define MFMA __builtin_amdgcn_mfma_f32_16x16x32_bf16

// ---------------------------------------------------------------------------
// prep: fused  [blocks 0..2047]  lora_t : abf = bf16(input), t = input@lora_right
//              [blocks 2048..4095] convert_w : wbf = bf16(weight)
//              [blocks 4096..4127] gram partials : G[b] = L L^T (per 256-col chunk)
// ---------------------------------------------------------------------------
__global__ __launch_bounds__(256) void prep_kernel(
    const float* __restrict__ inp, const float* __restrict__ wgt,
    const float* __restrict__ lright, const float* __restrict__ lleft,
    __bf16* __restrict__ abf, __bf16* __restrict__ wbf,
    float* __restrict__ tout, float* __restrict__ gpart) {
    __shared__ float sm[4096];
    const int bid = blockIdx.x;
    const int tid = threadIdx.x;

    if (bid < 2048) {
        // ---- lora_t role: 4 token rows per block ----
        const int row0 = bid * 4;
        const int b = row0 >> 11;
        const float* rb = lright + (size_t)b * 2048 * 16;

        float x[4][8];
        #pragma unroll
        for (int rr = 0; rr < 4; ++rr) {
            const float* p = inp + (size_t)(row0 + rr) * 2048 + tid * 8;
            float4 a0 = *(const float4*)p;
            float4 a1 = *(const float4*)(p + 4);
            x[rr][0] = a0.x; x[rr][1] = a0.y; x[rr][2] = a0.z; x[rr][3] = a0.w;
            x[rr][4] = a1.x; x[rr][5] = a1.y; x[rr][6] = a1.z; x[rr][7] = a1.w;
            bf16v8 v;
            #pragma unroll
            for (int i = 0; i < 8; ++i) v[i] = (__bf16)x[rr][i];
            *(bf16v8*)(abf + (size_t)(row0 + rr) * 2048 + tid * 8) = v;
        }

        float acc[4][16];
        #pragma unroll
        for (int rr = 0; rr < 4; ++rr)
            #pragma unroll
            for (int k = 0; k < 16; ++k) acc[rr][k] = 0.f;

        #pragma unroll
        for (int i = 0; i < 8; ++i) {
            const int d = tid * 8 + i;
            const float* rrow = rb + (size_t)d * 16;
            float4 r0 = *(const float4*)(rrow);
            float4 r1 = *(const float4*)(rrow + 4);
            float4 r2 = *(const float4*)(rrow + 8);
            float4 r3 = *(const float4*)(rrow + 12);
            float rv[16] = {r0.x, r0.y, r0.z, r0.w, r1.x, r1.y, r1.z, r1.w,
                            r2.x, r2.y, r2.z, r2.w, r3.x, r3.y, r3.z, r3.w};
            #pragma unroll
            for (int rr = 0; rr < 4; ++rr)
                #pragma unroll
                for (int k = 0; k < 16; ++k) acc[rr][k] += x[rr][i] * rv[k];
        }

        for (int rr = 0; rr < 4; ++rr) {
            #pragma unroll
            for (int k = 0; k < 16; ++k) sm[tid * 16 + k] = acc[rr][k];
            __syncthreads();
            if (tid < 128) {
                #pragma unroll
                for (int k = 0; k < 16; ++k)
                    sm[tid * 16 + k] += sm[(tid + 128) * 16 + k];
            }
            __syncthreads();
            if (tid < 32) {
                #pragma unroll
                for (int k = 0; k < 16; ++k)
                    sm[tid * 16 + k] += sm[(tid + 32) * 16 + k] +
                                        sm[(tid + 64) * 16 + k] +
                                        sm[(tid + 96) * 16 + k];
            }
            __syncthreads();
            if (tid < 16) {
                float s = 0.f;
                #pragma unroll
                for (int i = 0; i < 32; ++i) s += sm[i * 16 + tid];
                tout[(size_t)(row0 + rr) * 16 + tid] = s;
            }
            __syncthreads();
        }
    } else if (bid < 4096) {
        // ---- convert_w role ----
        const int i = ((bid - 2048) * 256 + tid) * 8;
        float4 x0 = *(const float4*)(wgt + i);
        float4 x1 = *(const float4*)(wgt + i + 4);
        bf16v8 v;
        v[0] = (__bf16)x0.x; v[1] = (__bf16)x0.y; v[2] = (__bf16)x0.z; v[3] = (__bf16)x0.w;
        v[4] = (__bf16)x1.x; v[5] = (__bf16)x1.y; v[6] = (__bf16)x1.z; v[7] = (__bf16)x1.w;
        *(bf16v8*)(wbf + i) = v;
    } else {
        // ---- gram role ----
        const int g = bid - 4096;
        const int b = g >> 3, c = g & 7;
        const int k = tid >> 4, j = tid & 15;
        const float* pk = lleft + ((size_t)b * 16 + k) * 2048 + c * 256;
        const float* pj = lleft + ((size_t)b * 16 + j) * 2048 + c * 256;
        float s = 0.f;
        #pragma unroll 4
        for (int r = 0; r < 256; r += 4) {
            float4 a = *(const float4*)(pk + r);
            float4 d = *(const float4*)(pj + r);
            s += a.x * d.x + a.y * d.y + a.z * d.z + a.w * d.w;
        }
        gpart[((size_t)b * 8 + c) * 256 + tid] = s;
    }
}

// ---------------------------------------------------------------------------
// norm: fold Gram partials; t' = SCALE * t * rsqrt(t^T G t)  (in place)
// ---------------------------------------------------------------------------
__global__ __launch_bounds__(256) void norm_kernel(
    const float* __restrict__ gpart, float* __restrict__ t) {
    __shared__ float gs[256];
    const int tid = threadIdx.x;
    const int tok0 = blockIdx.x * 256;
    const int b = tok0 >> 11;
    float g = 0.f;
    #pragma unroll
    for (int c = 0; c < 8; ++c) g += gpart[((size_t)b * 8 + c) * 256 + tid];
    gs[tid] = g;
    __syncthreads();

    float* tp = t + (size_t)(tok0 + tid) * 16;
    float tv[16];
    {
        float4 a0 = *(const float4*)(tp);
        float4 a1 = *(const float4*)(tp + 4);
        float4 a2 = *(const float4*)(tp + 8);
        float4 a3 = *(const float4*)(tp + 12);
        tv[0]=a0.x; tv[1]=a0.y; tv[2]=a0.z; tv[3]=a0.w;
        tv[4]=a1.x; tv[5]=a1.y; tv[6]=a1.z; tv[7]=a1.w;
        tv[8]=a2.x; tv[9]=a2.y; tv[10]=a2.z; tv[11]=a2.w;
        tv[12]=a3.x; tv[13]=a3.y; tv[14]=a3.z; tv[15]=a3.w;
    }
    float q = 0.f;
    #pragma unroll
    for (int k = 0; k < 16; ++k) {
        float s = 0.f;
        #pragma unroll
        for (int j = 0; j < 16; ++j) s += gs[k * 16 + j] * tv[j];
        q += tv[k] * s;
    }
    const float r = SCALE_V * rsqrtf(q);
    float4 o;
    o.x = tv[0]*r;  o.y = tv[1]*r;  o.z = tv[2]*r;  o.w = tv[3]*r;  *(float4*)(tp)      = o;
    o.x = tv[4]*r;  o.y = tv[5]*r;  o.z = tv[6]*r;  o.w = tv[7]*r;  *(float4*)(tp + 4)  = o;
    o.x = tv[8]*r;  o.y = tv[9]*r;  o.z = tv[10]*r; o.w = tv[11]*r; *(float4*)(tp + 8)  = o;
    o.x = tv[12]*r; o.y = tv[13]*r; o.z = tv[14]*r; o.w = tv[15]*r; *(float4*)(tp + 12) = o;
}

// ---------------------------------------------------------------------------
// gemm: 256x256 tile, BK=64, 8 waves (2Mx4N), 8-phase (4 phases/K-tile x 2 dbuf),
// counted vmcnt(6), XOR LDS swizzle, setprio around MFMA clusters.
// Epilogue: zero-padded K=32 LoRA MFMA extension + bias.
// ---------------------------------------------------------------------------
__global__ __launch_bounds__(512, 2) void gemm_ep_kernel(
    const __bf16* __restrict__ abf, const __bf16* __restrict__ wbf,
    const float* __restrict__ bias, const float* __restrict__ tpr,
    const float* __restrict__ lleft, float* __restrict__ out) {
    __shared__ __attribute__((aligned(16))) char smem[131072];  // As[2][256][64] | Bs[2][256][64] bf16

    const int tid  = threadIdx.x;
    const int w    = tid >> 6;           // wave 0..7
    const int lane = tid & 63;
    const int l3   = lane >> 3, l7 = lane & 7;
    const int wm   = w >> 2;             // 0..1 (M half)
    const int wn   = w & 3;              // 0..3 (N quarter)
    const int fr   = lane & 15;

    // XCD-swizzled tile assignment (256 wgs, 8 XCDs -> tile_n = XCD)
    const int tile_n = blockIdx.x & 7;
    const int tile_m = blockIdx.x >> 3;
    const int row0 = tile_m * 256;
    const int col0 = tile_n * 256;

    // staging: pre-swizzled global source column
    const int cswz = ((l7 ^ l3) * 8);                       // elements
    const size_t aG0 = (size_t)(row0 + 8 * w + l3) * 2048 + cswz;
    const int bCh = 64 * (w >> 2) + 8 * (w & 3);
    const size_t bG0 = (size_t)(col0 + bCh + l3) * 2048 + cswz;
    char* const aDst = smem + 8 * w * 128 + lane * 16;
    char* const bDst = smem + 65536 + bCh * 128 + lane * 16;

#define STAGE_A(BUFOFF, S, KKEL)                                                         \
    do {                                                                                 \
        ASYNC_COPY16(abf + aG0 + (size_t)((S)*64) * 2048 + (KKEL),  aDst + (BUFOFF) + (S)*8192);          \
        ASYNC_COPY16(abf + aG0 + (size_t)((S)*64 + 128) * 2048 + (KKEL), aDst + (BUFOFF) + (S)*8192 + 16384); \
    } while (0)
#define STAGE_B(BUFOFF, S, KKEL)                                                         \
    do {                                                                                 \
        ASYNC_COPY16(wbf + bG0 + (size_t)((S)*32) * 2048 + (KKEL),  bDst + (BUFOFF) + (S)*4096);          \
        ASYNC_COPY16(wbf + bG0 + (size_t)((S)*32 + 128) * 2048 + (KKEL), bDst + (BUFOFF) + (S)*4096 + 16384); \
    } while (0)

    // fragment read bases (byte addrs), swizzled k-offset per lane
    const int kx0 = (((lane >> 4) * 16) ^ (l7 << 4));
    const int kx1 = ((64 + (lane >> 4) * 16) ^ (l7 << 4));
    const char* const aRd = smem + (wm * 128 + fr) * 128;
    const char* const bRd = smem + 65536 + (wn * 64 + fr) * 128;

    f32v4 acc[8][4];
    #pragma unroll
    for (int m = 0; m < 8; ++m)
        #pragma unroll
        for (int n = 0; n < 4; ++n) {
            acc[m][n][0] = 0.f; acc[m][n][1] = 0.f;
            acc[m][n][2] = 0.f; acc[m][n][3] = 0.f;
        }

    // ---- prologue: stage kt0 fully + kt1 {B-lo, B-hi, A-lo} ----
    STAGE_A(0, 0, 0);      // A-Mlo(0)
    STAGE_B(0, 0, 0);      // B-Nlo(0)
    STAGE_B(0, 1, 0);      // B-Nhi(0)
    STAGE_A(0, 1, 0);      // A-Mhi(0)
    STAGE_B(32768, 0, 64); // B-Nlo(1)
    STAGE_B(32768, 1, 64); // B-Nhi(1)
    STAGE_A(32768, 0, 64); // A-Mlo(1)
    asm volatile("s_waitcnt vmcnt(6)" ::: "memory");
    FENCE(); __builtin_amdgcn_s_barrier(); FENCE();

    for (int kt = 0; kt < 32; ++kt) {
        const int bo = (kt & 1) * 32768;
        const int bn = bo ^ 32768;
        const size_t kk1 = (size_t)((kt + 1) & 31) * 64;
        const size_t kk2 = (size_t)((kt + 2) & 31) * 64;
        bf16v8 af[4][2], bl[2][2], bh[2][2];

        // ===== phase 1: read A-Mlo + B-Nlo; stage A-Mhi(kt+1); MFMA m0-3 x n0-1 =====
        #pragma unroll
        for (int m = 0; m < 4; ++m) {
            af[m][0] = *(const bf16v8*)(aRd + bo + m * 2048 + kx0);
            af[m][1] = *(const bf16v8*)(aRd + bo + m * 2048 + kx1);
        }
        #pragma unroll
        for (int n = 0; n < 2; ++n) {
            bl[n][0] = *(const bf16v8*)(bRd + bo + n * 2048 + kx0);
            bl[n][1] = *(const bf16v8*)(bRd + bo + n * 2048 + kx1);
        }
        STAGE_A(bn, 1, kk1);
        FENCE(); __builtin_amdgcn_s_barrier(); FENCE();
        __builtin_amdgcn_s_setprio(1);
        #pragma unroll
        for (int m = 0; m < 4; ++m)
            #pragma unroll
            for (int n = 0; n < 2; ++n) {
                acc[m][n] = MFMA(af[m][0], bl[n][0], acc[m][n], 0, 0, 0);
                acc[m][n] = MFMA(af[m][1], bl[n][1], acc[m][n], 0, 0, 0);
            }
        __builtin_amdgcn_s_setprio(0);
        FENCE(); __builtin_amdgcn_s_barrier(); FENCE();

        // ===== phase 2: read B-Nhi; stage B-Nlo(kt+2); MFMA m0-3 x n2-3 =====
        #pragma unroll
        for (int n = 0; n < 2; ++n) {
            bh[n][0] = *(const bf16v8*)(bRd + bo + (n + 2) * 2048 + kx0);
            bh[n][1] = *(const bf16v8*)(bRd + bo + (n + 2) * 2048 + kx1);
        }
        STAGE_B(bo, 0, kk2);
        FENCE(); __builtin_amdgcn_s_barrier(); FENCE();
        __builtin_amdgcn_s_setprio(1);
        #pragma unroll
        for (int m = 0; m < 4; ++m)
            #pragma unroll
            for (int n = 0; n < 2; ++n) {
                acc[m][n + 2] = MFMA(af[m][0], bh[n][0], acc[m][n + 2], 0, 0, 0);
                acc[m][n + 2] = MFMA(af[m][1], bh[n][1], acc[m][n + 2], 0, 0, 0);
            }
        __builtin_amdgcn_s_setprio(0);
        FENCE(); __builtin_amdgcn_s_barrier(); FENCE();

        // ===== phase 3: read A-Mhi; stage B-Nhi(kt+2); MFMA m4-7 x n2-3 =====
        #pragma unroll
        for (int m = 0; m < 4; ++m) {
            af[m][0] = *(const bf16v8*)(aRd + bo + (m + 4) * 2048 + kx0);
            af[m][1] = *(const bf16v8*)(aRd + bo + (m + 4) * 2048 + kx1);
        }
        STAGE_B(bo, 1, kk2);
        FENCE(); __builtin_amdgcn_s_barrier(); FENCE();
        __builtin_amdgcn_s_setprio(1);
        #pragma unroll
        for (int m = 0; m < 4; ++m)
            #pragma unroll
            for (int n = 0; n < 2; ++n) {
                acc[m + 4][n + 2] = MFMA(af[m][0], bh[n][0], acc[m + 4][n + 2], 0, 0, 0);
                acc[m + 4][n + 2] = MFMA(af[m][1], bh[n][1], acc[m + 4][n + 2], 0, 0, 0);
            }
        __builtin_amdgcn_s_setprio(0);
        FENCE(); __builtin_amdgcn_s_barrier(); FENCE();

        // ===== phase 4: stage A-Mlo(kt+2); vmcnt(6); MFMA m4-7 x n0-1 =====
        STAGE_A(bo, 0, kk2);
        asm volatile("s_waitcnt vmcnt(6)" ::: "memory");
        FENCE(); __builtin_amdgcn_s_barrier(); FENCE();
        __builtin_amdgcn_s_setprio(1);
        #pragma unroll
        for (int m = 0; m < 4; ++m)
            #pragma unroll
            for (int n = 0; n < 2; ++n) {
                acc[m + 4][n] = MFMA(af[m][0], bl[n][0], acc[m + 4][n], 0, 0, 0);
                acc[m + 4][n] = MFMA(af[m][1], bl[n][1], acc[m + 4][n], 0, 0, 0);
            }
        __builtin_amdgcn_s_setprio(0);
        FENCE(); __builtin_amdgcn_s_barrier(); FENCE();
    }

    // ---- LoRA extension: one zero-padded K=32 MFMA per fragment ----
    asm volatile("s_waitcnt vmcnt(0)" ::: "memory");
    __syncthreads();
    {
        const int r = tid >> 1;
        const int h = (tid & 1) * 8;
        bf16v8 zv;
        #pragma unroll
        for (int i = 0; i < 8; ++i) zv[i] = (__bf16)0.f;

        __bf16* tE = (__bf16*)smem;            // [256][40] bf16 (pad 8)
        __bf16* LE = (__bf16*)(smem + 20480);  // [256][40]

        const float* tp = tpr + (size_t)(row0 + r) * 16 + h;
        float4 t0 = *(const float4*)tp;
        float4 t1 = *(const float4*)(tp + 4);
        bf16v8 tv;
        tv[0]=(__bf16)t0.x; tv[1]=(__bf16)t0.y; tv[2]=(__bf16)t0.z; tv[3]=(__bf16)t0.w;
        tv[4]=(__bf16)t1.x; tv[5]=(__bf16)t1.y; tv[6]=(__bf16)t1.z; tv[7]=(__bf16)t1.w;
        *(bf16v8*)(tE + r * 40 + h) = tv;
        *(bf16v8*)(tE + r * 40 + 16 + h) = zv;

        const int bb = row0 >> 11;
        const float* lp = lleft + ((size_t)bb * 16 + h) * 2048 + col0 + r;
        bf16v8 lv;
        #pragma unroll
        for (int i = 0; i < 8; ++i) lv[i] = (__bf16)lp[(size_t)i * 2048];
        *(bf16v8*)(LE + r * 40 + h) = lv;
        *(bf16v8*)(LE + r * 40 + 16 + h) = zv;
    }
    __syncthreads();
    {
        const __bf16* tE = (const __bf16*)smem;
        const __bf16* LE = (const __bf16*)(smem + 20480);
        const int ko = (lane >> 4) * 8;
        bf16v8 bE[4];
        #pragma unroll
        for (int n = 0; n < 4; ++n)
            bE[n] = *(const bf16v8*)(LE + (wn * 64 + n * 16 + fr) * 40 + ko);
        #pragma unroll
        for (int m = 0; m < 8; ++m) {
            bf16v8 aE = *(const bf16v8*)(tE + (wm * 128 + m * 16 + fr) * 40 + ko);
            #pragma unroll
            for (int n = 0; n < 4; ++n)
                acc[m][n] = MFMA(aE, bE[n], acc[m][n], 0, 0, 0);
        }
    }

    // ---- writeout + bias ----
    #pragma unroll
    for (int n = 0; n < 4; ++n) {
        const int gc = col0 + wn * 64 + n * 16 + fr;
        const float bv = bias[gc];
        #pragma unroll
        for (int m = 0; m < 8; ++m) {
            #pragma unroll
            for (int j = 0; j < 4; ++j) {
                const int gr = row0 + wm * 128 + m * 16 + (lane >> 4) * 4 + j;
                out[(size_t)gr * 2048 + gc] = acc[m][n][j] + bv;
            }
        }
    }
#undef STAGE_A
#undef STAGE_B
}

// ---------------------------------------------------------------------------
extern "C" void kernel_launch(void* const* d_in, const int* in_sizes, int n_in,
                              void* d_out, int out_size, void* d_ws, size_t ws_size,
                              hipStream_t stream) {
    const float* inp  = (const float*)d_in[0];   // [4,2048,2048]
    const float* wgt  = (const float*)d_in[1];   // [2048,2048]
    const float* bias = (const float*)d_in[2];   // [2048]
    const float* lrt  = (const float*)d_in[3];   // [4,2048,16]
    const float* llf  = (const float*)d_in[4];   // [4,16,2048]
    float* out = (float*)d_out;                  // [4,2048,2048]

    char* ws = (char*)d_ws;
    __bf16* abf  = (__bf16*)ws;                    // 33,554,432 B
    __bf16* wbf  = (__bf16*)(ws + 33554432);       //  8,388,608 B
    float*  tbuf = (float*)(ws + 41943040);        //    524,288 B
    float*  gprt = (float*)(ws + 42467328);        //     32,768 B

    prep_kernel<<<4128, 256, 0, stream>>>(inp, wgt, lrt, llf, abf, wbf, tbuf, gprt);
    norm_kernel<<<32, 256, 0, stream>>>(gprt, tbuf);
    gemm_ep_kernel<<<dim3(256), 512, 0, stream>>>(abf, wbf, bias, tbuf, llf, out);
}

// Round 4
// 128.898 us; speedup vs baseline: 1.4005x; 1.0337x over previous
//
#include <hip/hip_runtime.h>
#include <hip/hip_bf16.h>

// Shapes fixed by reference: B=4, S=2048, D=K=2048, R=N=2048, LR=16, M=B*S=8192
#define SCALE_V 1.0f

typedef __bf16 bf16v8 __attribute__((ext_vector_type(8)));
typedef float f32v4 __attribute__((ext_vector_type(4)));

typedef const __attribute__((address_space(1))) void* gas_t;
typedef __attribute__((address_space(3))) void* las_t;
#define ASYNC_COPY16(g, l) \
    __builtin_amdgcn_global_load_lds((gas_t)(g), (las_t)(l), 16, 0, 0)
#define FENCE() asm volatile("" ::: "memory")
#define MFMA __builtin_amdgcn_mfma_f32_16x16x32_bf16

// ---------------------------------------------------------------------------
// prep: fused  [blocks 0..2047]  lora_t : abf = bf16(input), t = input@lora_right
//              [blocks 2048..4095] convert_w : wbf = bf16(weight)
//              [blocks 4096..4127] gram partials : G[b] = L L^T (per 256-col chunk)
// ---------------------------------------------------------------------------
__global__ __launch_bounds__(256) void prep_kernel(
    const float* __restrict__ inp, const float* __restrict__ wgt,
    const float* __restrict__ lright, const float* __restrict__ lleft,
    __bf16* __restrict__ abf, __bf16* __restrict__ wbf,
    float* __restrict__ tout, float* __restrict__ gpart) {
    __shared__ float sm[256];
    const int bid = blockIdx.x;
    const int tid = threadIdx.x;

    if (bid < 2048) {
        // ---- lora_t role: 4 token rows per block; thread owns d in [tid*8, tid*8+8) ----
        const int row0 = bid * 4;
        const int b = row0 >> 11;
        const float* rb = lright + (size_t)b * 2048 * 16;

        float x[4][8];
        #pragma unroll
        for (int rr = 0; rr < 4; ++rr) {
            const float* p = inp + (size_t)(row0 + rr) * 2048 + tid * 8;
            float4 a0 = *(const float4*)p;
            float4 a1 = *(const float4*)(p + 4);
            x[rr][0] = a0.x; x[rr][1] = a0.y; x[rr][2] = a0.z; x[rr][3] = a0.w;
            x[rr][4] = a1.x; x[rr][5] = a1.y; x[rr][6] = a1.z; x[rr][7] = a1.w;
            bf16v8 v;
            #pragma unroll
            for (int i = 0; i < 8; ++i) v[i] = (__bf16)x[rr][i];
            *(bf16v8*)(abf + (size_t)(row0 + rr) * 2048 + tid * 8) = v;
        }

        // acc flat: v[rr*16 + k]
        float v[64];
        #pragma unroll
        for (int i = 0; i < 64; ++i) v[i] = 0.f;

        #pragma unroll
        for (int i = 0; i < 8; ++i) {
            const int d = tid * 8 + i;
            const float* rrow = rb + (size_t)d * 16;
            float4 r0 = *(const float4*)(rrow);
            float4 r1 = *(const float4*)(rrow + 4);
            float4 r2 = *(const float4*)(rrow + 8);
            float4 r3 = *(const float4*)(rrow + 12);
            float rv[16] = {r0.x, r0.y, r0.z, r0.w, r1.x, r1.y, r1.z, r1.w,
                            r2.x, r2.y, r2.z, r2.w, r3.x, r3.y, r3.z, r3.w};
            #pragma unroll
            for (int rr = 0; rr < 4; ++rr)
                #pragma unroll
                for (int k = 0; k < 16; ++k) v[rr * 16 + k] += x[rr][i] * rv[k];
        }

        // ---- in-register butterfly reduce-scatter over 64 lanes ----
        // Step s keeps LOWER half on (lane&s)==0 and UPPER half on (lane&s)!=0,
        // so step s=1 decides index bit 5, s=2 bit 4, ... s=32 bit 0:
        // after 6 steps lane l holds the wave-sum of flat index rev6(l).
        const int lane = tid & 63;
        const int w = tid >> 6;
        #pragma unroll
        for (int s = 1, cnt = 64; s < 64; s <<= 1, cnt >>= 1) {
            const int half = cnt >> 1;
            const bool up = (lane & s) != 0;
            #pragma unroll
            for (int i = 0; i < 32; ++i) {
                if (i < half) {
                    float keep = up ? v[i + half] : v[i];
                    float give = up ? v[i] : v[i + half];
                    v[i] = keep + __shfl_xor(give, s, 64);
                }
            }
        }
        const int rev = ((lane & 1) << 5) | ((lane & 2) << 3) | ((lane & 4) << 1) |
                        ((lane & 8) >> 1) | ((lane & 16) >> 3) | ((lane & 32) >> 5);
        sm[w * 64 + rev] = v[0];
        __syncthreads();
        if (tid < 64) {
            tout[(size_t)row0 * 16 + tid] =
                sm[tid] + sm[64 + tid] + sm[128 + tid] + sm[192 + tid];
        }
    } else if (bid < 4096) {
        // ---- convert_w role ----
        const int i = ((bid - 2048) * 256 + tid) * 8;
        float4 x0 = *(const float4*)(wgt + i);
        float4 x1 = *(const float4*)(wgt + i + 4);
        bf16v8 v;
        v[0] = (__bf16)x0.x; v[1] = (__bf16)x0.y; v[2] = (__bf16)x0.z; v[3] = (__bf16)x0.w;
        v[4] = (__bf16)x1.x; v[5] = (__bf16)x1.y; v[6] = (__bf16)x1.z; v[7] = (__bf16)x1.w;
        *(bf16v8*)(wbf + i) = v;
    } else {
        // ---- gram role ----
        const int g = bid - 4096;
        const int b = g >> 3, c = g & 7;
        const int k = tid >> 4, j = tid & 15;
        const float* pk = lleft + ((size_t)b * 16 + k) * 2048 + c * 256;
        const float* pj = lleft + ((size_t)b * 16 + j) * 2048 + c * 256;
        float s = 0.f;
        #pragma unroll 4
        for (int r = 0; r < 256; r += 4) {
            float4 a = *(const float4*)(pk + r);
            float4 d = *(const float4*)(pj + r);
            s += a.x * d.x + a.y * d.y + a.z * d.z + a.w * d.w;
        }
        gpart[((size_t)b * 8 + c) * 256 + tid] = s;
    }
}

// ---------------------------------------------------------------------------
// norm: fold Gram partials; t' = SCALE * t * rsqrt(t^T G t)  (in place)
// ---------------------------------------------------------------------------
__global__ __launch_bounds__(256) void norm_kernel(
    const float* __restrict__ gpart, float* __restrict__ t) {
    __shared__ float gs[256];
    const int tid = threadIdx.x;
    const int tok0 = blockIdx.x * 256;
    const int b = tok0 >> 11;
    float g = 0.f;
    #pragma unroll
    for (int c = 0; c < 8; ++c) g += gpart[((size_t)b * 8 + c) * 256 + tid];
    gs[tid] = g;
    __syncthreads();

    float* tp = t + (size_t)(tok0 + tid) * 16;
    float tv[16];
    {
        float4 a0 = *(const float4*)(tp);
        float4 a1 = *(const float4*)(tp + 4);
        float4 a2 = *(const float4*)(tp + 8);
        float4 a3 = *(const float4*)(tp + 12);
        tv[0]=a0.x; tv[1]=a0.y; tv[2]=a0.z; tv[3]=a0.w;
        tv[4]=a1.x; tv[5]=a1.y; tv[6]=a1.z; tv[7]=a1.w;
        tv[8]=a2.x; tv[9]=a2.y; tv[10]=a2.z; tv[11]=a2.w;
        tv[12]=a3.x; tv[13]=a3.y; tv[14]=a3.z; tv[15]=a3.w;
    }
    float q = 0.f;
    #pragma unroll
    for (int k = 0; k < 16; ++k) {
        float s = 0.f;
        #pragma unroll
        for (int j = 0; j < 16; ++j) s += gs[k * 16 + j] * tv[j];
        q += tv[k] * s;
    }
    const float r = SCALE_V * rsqrtf(q);
    float4 o;
    o.x = tv[0]*r;  o.y = tv[1]*r;  o.z = tv[2]*r;  o.w = tv[3]*r;  *(float4*)(tp)      = o;
    o.x = tv[4]*r;  o.y = tv[5]*r;  o.z = tv[6]*r;  o.w = tv[7]*r;  *(float4*)(tp + 4)  = o;
    o.x = tv[8]*r;  o.y = tv[9]*r;  o.z = tv[10]*r; o.w = tv[11]*r; *(float4*)(tp + 8)  = o;
    o.x = tv[12]*r; o.y = tv[13]*r; o.z = tv[14]*r; o.w = tv[15]*r; *(float4*)(tp + 12) = o;
}

// ---------------------------------------------------------------------------
// gemm: 256x256 tile, BK=64, 8 waves (2Mx4N), 8-phase (4 phases/K-tile x 2 dbuf),
// counted vmcnt(6), XOR LDS swizzle, setprio around MFMA clusters.
// Epilogue: zero-padded K=32 LoRA MFMA extension + bias.  (unchanged from R2)
// ---------------------------------------------------------------------------
__global__ __launch_bounds__(512, 2) void gemm_ep_kernel(
    const __bf16* __restrict__ abf, const __bf16* __restrict__ wbf,
    const float* __restrict__ bias, const float* __restrict__ tpr,
    const float* __restrict__ lleft, float* __restrict__ out) {
    __shared__ __attribute__((aligned(16))) char smem[131072];  // As[2][256][64] | Bs[2][256][64] bf16

    const int tid  = threadIdx.x;
    const int w    = tid >> 6;           // wave 0..7
    const int lane = tid & 63;
    const int l3   = lane >> 3, l7 = lane & 7;
    const int wm   = w >> 2;             // 0..1 (M half)
    const int wn   = w & 3;              // 0..3 (N quarter)
    const int fr   = lane & 15;

    // XCD-swizzled tile assignment (256 wgs, 8 XCDs -> tile_n = XCD)
    const int tile_n = blockIdx.x & 7;
    const int tile_m = blockIdx.x >> 3;
    const int row0 = tile_m * 256;
    const int col0 = tile_n * 256;

    // staging: pre-swizzled global source column
    const int cswz = ((l7 ^ l3) * 8);                       // elements
    const size_t aG0 = (size_t)(row0 + 8 * w + l3) * 2048 + cswz;
    const int bCh = 64 * (w >> 2) + 8 * (w & 3);
    const size_t bG0 = (size_t)(col0 + bCh + l3) * 2048 + cswz;
    char* const aDst = smem + 8 * w * 128 + lane * 16;
    char* const bDst = smem + 65536 + bCh * 128 + lane * 16;

#define STAGE_A(BUFOFF, S, KKEL)                                                         \
    do {                                                                                 \
        ASYNC_COPY16(abf + aG0 + (size_t)((S)*64) * 2048 + (KKEL),  aDst + (BUFOFF) + (S)*8192);          \
        ASYNC_COPY16(abf + aG0 + (size_t)((S)*64 + 128) * 2048 + (KKEL), aDst + (BUFOFF) + (S)*8192 + 16384); \
    } while (0)
#define STAGE_B(BUFOFF, S, KKEL)                                                         \
    do {                                                                                 \
        ASYNC_COPY16(wbf + bG0 + (size_t)((S)*32) * 2048 + (KKEL),  bDst + (BUFOFF) + (S)*4096);          \
        ASYNC_COPY16(wbf + bG0 + (size_t)((S)*32 + 128) * 2048 + (KKEL), bDst + (BUFOFF) + (S)*4096 + 16384); \
    } while (0)

    // fragment read bases (byte addrs), swizzled k-offset per lane
    const int kx0 = (((lane >> 4) * 16) ^ (l7 << 4));
    const int kx1 = ((64 + (lane >> 4) * 16) ^ (l7 << 4));
    const char* const aRd = smem + (wm * 128 + fr) * 128;
    const char* const bRd = smem + 65536 + (wn * 64 + fr) * 128;

    f32v4 acc[8][4];
    #pragma unroll
    for (int m = 0; m < 8; ++m)
        #pragma unroll
        for (int n = 0; n < 4; ++n) {
            acc[m][n][0] = 0.f; acc[m][n][1] = 0.f;
            acc[m][n][2] = 0.f; acc[m][n][3] = 0.f;
        }

    // ---- prologue: stage kt0 fully + kt1 {B-lo, B-hi, A-lo} ----
    STAGE_A(0, 0, 0);      // A-Mlo(0)
    STAGE_B(0, 0, 0);      // B-Nlo(0)
    STAGE_B(0, 1, 0);      // B-Nhi(0)
    STAGE_A(0, 1, 0);      // A-Mhi(0)
    STAGE_B(32768, 0, 64); // B-Nlo(1)
    STAGE_B(32768, 1, 64); // B-Nhi(1)
    STAGE_A(32768, 0, 64); // A-Mlo(1)
    asm volatile("s_waitcnt vmcnt(6)" ::: "memory");
    FENCE(); __builtin_amdgcn_s_barrier(); FENCE();

    for (int kt = 0; kt < 32; ++kt) {
        const int bo = (kt & 1) * 32768;
        const int bn = bo ^ 32768;
        const size_t kk1 = (size_t)((kt + 1) & 31) * 64;
        const size_t kk2 = (size_t)((kt + 2) & 31) * 64;
        bf16v8 af[4][2], bl[2][2], bh[2][2];

        // ===== phase 1: read A-Mlo + B-Nlo; stage A-Mhi(kt+1); MFMA m0-3 x n0-1 =====
        #pragma unroll
        for (int m = 0; m < 4; ++m) {
            af[m][0] = *(const bf16v8*)(aRd + bo + m * 2048 + kx0);
            af[m][1] = *(const bf16v8*)(aRd + bo + m * 2048 + kx1);
        }
        #pragma unroll
        for (int n = 0; n < 2; ++n) {
            bl[n][0] = *(const bf16v8*)(bRd + bo + n * 2048 + kx0);
            bl[n][1] = *(const bf16v8*)(bRd + bo + n * 2048 + kx1);
        }
        STAGE_A(bn, 1, kk1);
        FENCE(); __builtin_amdgcn_s_barrier(); FENCE();
        __builtin_amdgcn_s_setprio(1);
        #pragma unroll
        for (int m = 0; m < 4; ++m)
            #pragma unroll
            for (int n = 0; n < 2; ++n) {
                acc[m][n] = MFMA(af[m][0], bl[n][0], acc[m][n], 0, 0, 0);
                acc[m][n] = MFMA(af[m][1], bl[n][1], acc[m][n], 0, 0, 0);
            }
        __builtin_amdgcn_s_setprio(0);
        FENCE(); __builtin_amdgcn_s_barrier(); FENCE();

        // ===== phase 2: read B-Nhi; stage B-Nlo(kt+2); MFMA m0-3 x n2-3 =====
        #pragma unroll
        for (int n = 0; n < 2; ++n) {
            bh[n][0] = *(const bf16v8*)(bRd + bo + (n + 2) * 2048 + kx0);
            bh[n][1] = *(const bf16v8*)(bRd + bo + (n + 2) * 2048 + kx1);
        }
        STAGE_B(bo, 0, kk2);
        FENCE(); __builtin_amdgcn_s_barrier(); FENCE();
        __builtin_amdgcn_s_setprio(1);
        #pragma unroll
        for (int m = 0; m < 4; ++m)
            #pragma unroll
            for (int n = 0; n < 2; ++n) {
                acc[m][n + 2] = MFMA(af[m][0], bh[n][0], acc[m][n + 2], 0, 0, 0);
                acc[m][n + 2] = MFMA(af[m][1], bh[n][1], acc[m][n + 2], 0, 0, 0);
            }
        __builtin_amdgcn_s_setprio(0);
        FENCE(); __builtin_amdgcn_s_barrier(); FENCE();

        // ===== phase 3: read A-Mhi; stage B-Nhi(kt+2); MFMA m4-7 x n2-3 =====
        #pragma unroll
        for (int m = 0; m < 4; ++m) {
            af[m][0] = *(const bf16v8*)(aRd + bo + (m + 4) * 2048 + kx0);
            af[m][1] = *(const bf16v8*)(aRd + bo + (m + 4) * 2048 + kx1);
        }
        STAGE_B(bo, 1, kk2);
        FENCE(); __builtin_amdgcn_s_barrier(); FENCE();
        __builtin_amdgcn_s_setprio(1);
        #pragma unroll
        for (int m = 0; m < 4; ++m)
            #pragma unroll
            for (int n = 0; n < 2; ++n) {
                acc[m + 4][n + 2] = MFMA(af[m][0], bh[n][0], acc[m + 4][n + 2], 0, 0, 0);
                acc[m + 4][n + 2] = MFMA(af[m][1], bh[n][1], acc[m + 4][n + 2], 0, 0, 0);
            }
        __builtin_amdgcn_s_setprio(0);
        FENCE(); __builtin_amdgcn_s_barrier(); FENCE();

        // ===== phase 4: stage A-Mlo(kt+2); vmcnt(6); MFMA m4-7 x n0-1 =====
        STAGE_A(bo, 0, kk2);
        asm volatile("s_waitcnt vmcnt(6)" ::: "memory");
        FENCE(); __builtin_amdgcn_s_barrier(); FENCE();
        __builtin_amdgcn_s_setprio(1);
        #pragma unroll
        for (int m = 0; m < 4; ++m)
            #pragma unroll
            for (int n = 0; n < 2; ++n) {
                acc[m + 4][n] = MFMA(af[m][0], bl[n][0], acc[m + 4][n], 0, 0, 0);
                acc[m + 4][n] = MFMA(af[m][1], bl[n][1], acc[m + 4][n], 0, 0, 0);
            }
        __builtin_amdgcn_s_setprio(0);
        FENCE(); __builtin_amdgcn_s_barrier(); FENCE();
    }

    // ---- LoRA extension: one zero-padded K=32 MFMA per fragment ----
    asm volatile("s_waitcnt vmcnt(0)" ::: "memory");
    __syncthreads();
    {
        const int r = tid >> 1;
        const int h = (tid & 1) * 8;
        bf16v8 zv;
        #pragma unroll
        for (int i = 0; i < 8; ++i) zv[i] = (__bf16)0.f;

        __bf16* tE = (__bf16*)smem;            // [256][40] bf16 (pad 8)
        __bf16* LE = (__bf16*)(smem + 20480);  // [256][40]

        const float* tp = tpr + (size_t)(row0 + r) * 16 + h;
        float4 t0 = *(const float4*)tp;
        float4 t1 = *(const float4*)(tp + 4);
        bf16v8 tv;
        tv[0]=(__bf16)t0.x; tv[1]=(__bf16)t0.y; tv[2]=(__bf16)t0.z; tv[3]=(__bf16)t0.w;
        tv[4]=(__bf16)t1.x; tv[5]=(__bf16)t1.y; tv[6]=(__bf16)t1.z; tv[7]=(__bf16)t1.w;
        *(bf16v8*)(tE + r * 40 + h) = tv;
        *(bf16v8*)(tE + r * 40 + 16 + h) = zv;

        const int bb = row0 >> 11;
        const float* lp = lleft + ((size_t)bb * 16 + h) * 2048 + col0 + r;
        bf16v8 lv;
        #pragma unroll
        for (int i = 0; i < 8; ++i) lv[i] = (__bf16)lp[(size_t)i * 2048];
        *(bf16v8*)(LE + r * 40 + h) = lv;
        *(bf16v8*)(LE + r * 40 + 16 + h) = zv;
    }
    __syncthreads();
    {
        const __bf16* tE = (const __bf16*)smem;
        const __bf16* LE = (const __bf16*)(smem + 20480);
        const int ko = (lane >> 4) * 8;
        bf16v8 bE[4];
        #pragma unroll
        for (int n = 0; n < 4; ++n)
            bE[n] = *(const bf16v8*)(LE + (wn * 64 + n * 16 + fr) * 40 + ko);
        #pragma unroll
        for (int m = 0; m < 8; ++m) {
            bf16v8 aE = *(const bf16v8*)(tE + (wm * 128 + m * 16 + fr) * 40 + ko);
            #pragma unroll
            for (int n = 0; n < 4; ++n)
                acc[m][n] = MFMA(aE, bE[n], acc[m][n], 0, 0, 0);
        }
    }

    // ---- writeout + bias ----
    #pragma unroll
    for (int n = 0; n < 4; ++n) {
        const int gc = col0 + wn * 64 + n * 16 + fr;
        const float bv = bias[gc];
        #pragma unroll
        for (int m = 0; m < 8; ++m) {
            #pragma unroll
            for (int j = 0; j < 4; ++j) {
                const int gr = row0 + wm * 128 + m * 16 + (lane >> 4) * 4 + j;
                out[(size_t)gr * 2048 + gc] = acc[m][n][j] + bv;
            }
        }
    }
#undef STAGE_A
#undef STAGE_B
}

// ---------------------------------------------------------------------------
extern "C" void kernel_launch(void* const* d_in, const int* in_sizes, int n_in,
                              void* d_out, int out_size, void* d_ws, size_t ws_size,
                              hipStream_t stream) {
    const float* inp  = (const float*)d_in[0];   // [4,2048,2048]
    const float* wgt  = (const float*)d_in[1];   // [2048,2048]
    const float* bias = (const float*)d_in[2];   // [2048]
    const float* lrt  = (const float*)d_in[3];   // [4,2048,16]
    const float* llf  = (const float*)d_in[4];   // [4,16,2048]
    float* out = (float*)d_out;                  // [4,2048,2048]

    char* ws = (char*)d_ws;
    __bf16* abf  = (__bf16*)ws;                    // 33,554,432 B
    __bf16* wbf  = (__bf16*)(ws + 33554432);       //  8,388,608 B
    float*  tbuf = (float*)(ws + 41943040);        //    524,288 B
    float*  gprt = (float*)(ws + 42467328);        //     32,768 B

    prep_kernel<<<4128, 256, 0, stream>>>(inp, wgt, lrt, llf, abf, wbf, tbuf, gprt);
    norm_kernel<<<32, 256, 0, stream>>>(gprt, tbuf);
    gemm_ep_kernel<<<dim3(256), 512, 0, stream>>>(abf, wbf, bias, tbuf, llf, out);
}

// Round 5
// 112.598 us; speedup vs baseline: 1.6033x; 1.1448x over previous
//
#include <hip/hip_runtime.h>
#include <hip/hip_bf16.h>

// Shapes fixed by reference: B=4, S=2048, D=K=2048, R=N=2048, LR=16, M=B*S=8192
#define SCALE_V 1.0f

typedef __bf16 bf16v8 __attribute__((ext_vector_type(8)));
typedef float f32v4 __attribute__((ext_vector_type(4)));

typedef const __attribute__((address_space(1))) void* gas_t;
typedef __attribute__((address_space(3))) void* las_t;
#define ASYNC_COPY16(g, l) \
    __builtin_amdgcn_global_load_lds((gas_t)(g), (las_t)(l), 16, 0, 0)
#define FENCE() asm volatile("" ::: "memory")
#define MFMA __builtin_amdgcn_mfma_f32_16x16x32_bf16

// ---------------------------------------------------------------------------
// transpose_lr: lrT[b][k][d] = lright[b][d][k]   (512 KB total, LDS-bounced)
// grid (8 d-blocks, 4 batches) x 256
// ---------------------------------------------------------------------------
__global__ __launch_bounds__(256) void transpose_lr_kernel(
    const float* __restrict__ lright, float* __restrict__ lrT) {
    __shared__ float tile[16][273];   // [k][d_local], pad 273 -> 16 distinct banks
    const int b = blockIdx.y;
    const int d0 = blockIdx.x * 256;
    const int t = threadIdx.x;
    const float* src = lright + (size_t)b * 32768 + (size_t)d0 * 16;
    #pragma unroll
    for (int j = 0; j < 16; ++j) {
        // flat e = j*256 + t :  k = e&15 = t&15 ; d_local = e>>4 = j*16 + (t>>4)
        tile[t & 15][j * 16 + (t >> 4)] = src[j * 256 + t];   // coalesced read
    }
    __syncthreads();
    const int k = t >> 4, dcol = t & 15;
    float* dst = lrT + (size_t)b * 32768 + (size_t)k * 2048 + d0;
    #pragma unroll
    for (int j = 0; j < 16; ++j) {
        dst[dcol + j * 16] = tile[k][dcol + j * 16];          // coalesced write
    }
}

// ---------------------------------------------------------------------------
// prep: fused  [blocks 0..2047]  lora_t : abf = bf16(input), t = input@lora_right
//              [blocks 2048..4095] convert_w : wbf = bf16(weight)
//              [blocks 4096..4127] gram partials : G[b] = L L^T (per 256-col chunk)
// ---------------------------------------------------------------------------
__global__ __launch_bounds__(256) void prep_kernel(
    const float* __restrict__ inp, const float* __restrict__ wgt,
    const float* __restrict__ lrT, const float* __restrict__ lleft,
    __bf16* __restrict__ abf, __bf16* __restrict__ wbf,
    float* __restrict__ tout, float* __restrict__ gpart) {
    __shared__ float sm[256];
    const int bid = blockIdx.x;
    const int tid = threadIdx.x;

    if (bid < 2048) {
        // ---- lora_t role: 4 token rows per block; thread owns d in [tid*8, tid*8+8) ----
        const int row0 = bid * 4;
        const int b = row0 >> 11;
        const float* lt = lrT + (size_t)b * 32768;   // [16][2048]

        float x[4][8];
        #pragma unroll
        for (int rr = 0; rr < 4; ++rr) {
            const float* p = inp + (size_t)(row0 + rr) * 2048 + tid * 8;
            float4 a0 = *(const float4*)p;
            float4 a1 = *(const float4*)(p + 4);
            x[rr][0] = a0.x; x[rr][1] = a0.y; x[rr][2] = a0.z; x[rr][3] = a0.w;
            x[rr][4] = a1.x; x[rr][5] = a1.y; x[rr][6] = a1.z; x[rr][7] = a1.w;
            bf16v8 v;
            #pragma unroll
            for (int i = 0; i < 8; ++i) v[i] = (__bf16)x[rr][i];
            *(bf16v8*)(abf + (size_t)(row0 + rr) * 2048 + tid * 8) = v;
        }

        // v[rr*16 + k] = dot8(x[rr], lrT[k][tid*8..+8]) — coalesced per-k loads
        float v[64];
        #pragma unroll
        for (int k = 0; k < 16; ++k) {
            const float* lp = lt + (size_t)k * 2048 + tid * 8;
            float4 l0 = *(const float4*)lp;
            float4 l1 = *(const float4*)(lp + 4);
            float lv[8] = {l0.x, l0.y, l0.z, l0.w, l1.x, l1.y, l1.z, l1.w};
            #pragma unroll
            for (int rr = 0; rr < 4; ++rr) {
                float s = 0.f;
                #pragma unroll
                for (int i = 0; i < 8; ++i) s += x[rr][i] * lv[i];
                v[rr * 16 + k] = s;
            }
        }

        // ---- in-register butterfly reduce-scatter over 64 lanes (verified R4) ----
        const int lane = tid & 63;
        const int w = tid >> 6;
        #pragma unroll
        for (int s = 1, cnt = 64; s < 64; s <<= 1, cnt >>= 1) {
            const int half = cnt >> 1;
            const bool up = (lane & s) != 0;
            #pragma unroll
            for (int i = 0; i < 32; ++i) {
                if (i < half) {
                    float keep = up ? v[i + half] : v[i];
                    float give = up ? v[i] : v[i + half];
                    v[i] = keep + __shfl_xor(give, s, 64);
                }
            }
        }
        const int rev = ((lane & 1) << 5) | ((lane & 2) << 3) | ((lane & 4) << 1) |
                        ((lane & 8) >> 1) | ((lane & 16) >> 3) | ((lane & 32) >> 5);
        sm[w * 64 + rev] = v[0];
        __syncthreads();
        if (tid < 64) {
            tout[(size_t)row0 * 16 + tid] =
                sm[tid] + sm[64 + tid] + sm[128 + tid] + sm[192 + tid];
        }
    } else if (bid < 4096) {
        // ---- convert_w role ----
        const int i = ((bid - 2048) * 256 + tid) * 8;
        float4 x0 = *(const float4*)(wgt + i);
        float4 x1 = *(const float4*)(wgt + i + 4);
        bf16v8 v;
        v[0] = (__bf16)x0.x; v[1] = (__bf16)x0.y; v[2] = (__bf16)x0.z; v[3] = (__bf16)x0.w;
        v[4] = (__bf16)x1.x; v[5] = (__bf16)x1.y; v[6] = (__bf16)x1.z; v[7] = (__bf16)x1.w;
        *(bf16v8*)(wbf + i) = v;
    } else {
        // ---- gram role ----
        const int g = bid - 4096;
        const int b = g >> 3, c = g & 7;
        const int k = tid >> 4, j = tid & 15;
        const float* pk = lleft + ((size_t)b * 16 + k) * 2048 + c * 256;
        const float* pj = lleft + ((size_t)b * 16 + j) * 2048 + c * 256;
        float s = 0.f;
        #pragma unroll 4
        for (int r = 0; r < 256; r += 4) {
            float4 a = *(const float4*)(pk + r);
            float4 d = *(const float4*)(pj + r);
            s += a.x * d.x + a.y * d.y + a.z * d.z + a.w * d.w;
        }
        gpart[((size_t)b * 8 + c) * 256 + tid] = s;
    }
}

// ---------------------------------------------------------------------------
// norm: fold Gram partials; t' = SCALE * t * rsqrt(t^T G t)  (in place)
// ---------------------------------------------------------------------------
__global__ __launch_bounds__(256) void norm_kernel(
    const float* __restrict__ gpart, float* __restrict__ t) {
    __shared__ float gs[256];
    const int tid = threadIdx.x;
    const int tok0 = blockIdx.x * 256;
    const int b = tok0 >> 11;
    float g = 0.f;
    #pragma unroll
    for (int c = 0; c < 8; ++c) g += gpart[((size_t)b * 8 + c) * 256 + tid];
    gs[tid] = g;
    __syncthreads();

    float* tp = t + (size_t)(tok0 + tid) * 16;
    float tv[16];
    {
        float4 a0 = *(const float4*)(tp);
        float4 a1 = *(const float4*)(tp + 4);
        float4 a2 = *(const float4*)(tp + 8);
        float4 a3 = *(const float4*)(tp + 12);
        tv[0]=a0.x; tv[1]=a0.y; tv[2]=a0.z; tv[3]=a0.w;
        tv[4]=a1.x; tv[5]=a1.y; tv[6]=a1.z; tv[7]=a1.w;
        tv[8]=a2.x; tv[9]=a2.y; tv[10]=a2.z; tv[11]=a2.w;
        tv[12]=a3.x; tv[13]=a3.y; tv[14]=a3.z; tv[15]=a3.w;
    }
    float q = 0.f;
    #pragma unroll
    for (int k = 0; k < 16; ++k) {
        float s = 0.f;
        #pragma unroll
        for (int j = 0; j < 16; ++j) s += gs[k * 16 + j] * tv[j];
        q += tv[k] * s;
    }
    const float r = SCALE_V * rsqrtf(q);
    float4 o;
    o.x = tv[0]*r;  o.y = tv[1]*r;  o.z = tv[2]*r;  o.w = tv[3]*r;  *(float4*)(tp)      = o;
    o.x = tv[4]*r;  o.y = tv[5]*r;  o.z = tv[6]*r;  o.w = tv[7]*r;  *(float4*)(tp + 4)  = o;
    o.x = tv[8]*r;  o.y = tv[9]*r;  o.z = tv[10]*r; o.w = tv[11]*r; *(float4*)(tp + 8)  = o;
    o.x = tv[12]*r; o.y = tv[13]*r; o.z = tv[14]*r; o.w = tv[15]*r; *(float4*)(tp + 12) = o;
}

// ---------------------------------------------------------------------------
// gemm: 256x256 tile, BK=64, 8 waves (2Mx4N), 8-phase (4 phases/K-tile x 2 dbuf),
// counted vmcnt(6), XOR LDS swizzle, setprio around MFMA clusters.
// Epilogue: zero-padded K=32 LoRA MFMA extension + bias.  (unchanged from R2)
// ---------------------------------------------------------------------------
__global__ __launch_bounds__(512, 2) void gemm_ep_kernel(
    const __bf16* __restrict__ abf, const __bf16* __restrict__ wbf,
    const float* __restrict__ bias, const float* __restrict__ tpr,
    const float* __restrict__ lleft, float* __restrict__ out) {
    __shared__ __attribute__((aligned(16))) char smem[131072];  // As[2][256][64] | Bs[2][256][64] bf16

    const int tid  = threadIdx.x;
    const int w    = tid >> 6;           // wave 0..7
    const int lane = tid & 63;
    const int l3   = lane >> 3, l7 = lane & 7;
    const int wm   = w >> 2;             // 0..1 (M half)
    const int wn   = w & 3;              // 0..3 (N quarter)
    const int fr   = lane & 15;

    // XCD-swizzled tile assignment (256 wgs, 8 XCDs -> tile_n = XCD)
    const int tile_n = blockIdx.x & 7;
    const int tile_m = blockIdx.x >> 3;
    const int row0 = tile_m * 256;
    const int col0 = tile_n * 256;

    // staging: pre-swizzled global source column
    const int cswz = ((l7 ^ l3) * 8);                       // elements
    const size_t aG0 = (size_t)(row0 + 8 * w + l3) * 2048 + cswz;
    const int bCh = 64 * (w >> 2) + 8 * (w & 3);
    const size_t bG0 = (size_t)(col0 + bCh + l3) * 2048 + cswz;
    char* const aDst = smem + 8 * w * 128 + lane * 16;
    char* const bDst = smem + 65536 + bCh * 128 + lane * 16;

#define STAGE_A(BUFOFF, S, KKEL)                                                         \
    do {                                                                                 \
        ASYNC_COPY16(abf + aG0 + (size_t)((S)*64) * 2048 + (KKEL),  aDst + (BUFOFF) + (S)*8192);          \
        ASYNC_COPY16(abf + aG0 + (size_t)((S)*64 + 128) * 2048 + (KKEL), aDst + (BUFOFF) + (S)*8192 + 16384); \
    } while (0)
#define STAGE_B(BUFOFF, S, KKEL)                                                         \
    do {                                                                                 \
        ASYNC_COPY16(wbf + bG0 + (size_t)((S)*32) * 2048 + (KKEL),  bDst + (BUFOFF) + (S)*4096);          \
        ASYNC_COPY16(wbf + bG0 + (size_t)((S)*32 + 128) * 2048 + (KKEL), bDst + (BUFOFF) + (S)*4096 + 16384); \
    } while (0)

    // fragment read bases (byte addrs), swizzled k-offset per lane
    const int kx0 = (((lane >> 4) * 16) ^ (l7 << 4));
    const int kx1 = ((64 + (lane >> 4) * 16) ^ (l7 << 4));
    const char* const aRd = smem + (wm * 128 + fr) * 128;
    const char* const bRd = smem + 65536 + (wn * 64 + fr) * 128;

    f32v4 acc[8][4];
    #pragma unroll
    for (int m = 0; m < 8; ++m)
        #pragma unroll
        for (int n = 0; n < 4; ++n) {
            acc[m][n][0] = 0.f; acc[m][n][1] = 0.f;
            acc[m][n][2] = 0.f; acc[m][n][3] = 0.f;
        }

    // ---- prologue: stage kt0 fully + kt1 {B-lo, B-hi, A-lo} ----
    STAGE_A(0, 0, 0);      // A-Mlo(0)
    STAGE_B(0, 0, 0);      // B-Nlo(0)
    STAGE_B(0, 1, 0);      // B-Nhi(0)
    STAGE_A(0, 1, 0);      // A-Mhi(0)
    STAGE_B(32768, 0, 64); // B-Nlo(1)
    STAGE_B(32768, 1, 64); // B-Nhi(1)
    STAGE_A(32768, 0, 64); // A-Mlo(1)
    asm volatile("s_waitcnt vmcnt(6)" ::: "memory");
    FENCE(); __builtin_amdgcn_s_barrier(); FENCE();

    for (int kt = 0; kt < 32; ++kt) {
        const int bo = (kt & 1) * 32768;
        const int bn = bo ^ 32768;
        const size_t kk1 = (size_t)((kt + 1) & 31) * 64;
        const size_t kk2 = (size_t)((kt + 2) & 31) * 64;
        bf16v8 af[4][2], bl[2][2], bh[2][2];

        // ===== phase 1: read A-Mlo + B-Nlo; stage A-Mhi(kt+1); MFMA m0-3 x n0-1 =====
        #pragma unroll
        for (int m = 0; m < 4; ++m) {
            af[m][0] = *(const bf16v8*)(aRd + bo + m * 2048 + kx0);
            af[m][1] = *(const bf16v8*)(aRd + bo + m * 2048 + kx1);
        }
        #pragma unroll
        for (int n = 0; n < 2; ++n) {
            bl[n][0] = *(const bf16v8*)(bRd + bo + n * 2048 + kx0);
            bl[n][1] = *(const bf16v8*)(bRd + bo + n * 2048 + kx1);
        }
        STAGE_A(bn, 1, kk1);
        FENCE(); __builtin_amdgcn_s_barrier(); FENCE();
        __builtin_amdgcn_s_setprio(1);
        #pragma unroll
        for (int m = 0; m < 4; ++m)
            #pragma unroll
            for (int n = 0; n < 2; ++n) {
                acc[m][n] = MFMA(af[m][0], bl[n][0], acc[m][n], 0, 0, 0);
                acc[m][n] = MFMA(af[m][1], bl[n][1], acc[m][n], 0, 0, 0);
            }
        __builtin_amdgcn_s_setprio(0);
        FENCE(); __builtin_amdgcn_s_barrier(); FENCE();

        // ===== phase 2: read B-Nhi; stage B-Nlo(kt+2); MFMA m0-3 x n2-3 =====
        #pragma unroll
        for (int n = 0; n < 2; ++n) {
            bh[n][0] = *(const bf16v8*)(bRd + bo + (n + 2) * 2048 + kx0);
            bh[n][1] = *(const bf16v8*)(bRd + bo + (n + 2) * 2048 + kx1);
        }
        STAGE_B(bo, 0, kk2);
        FENCE(); __builtin_amdgcn_s_barrier(); FENCE();
        __builtin_amdgcn_s_setprio(1);
        #pragma unroll
        for (int m = 0; m < 4; ++m)
            #pragma unroll
            for (int n = 0; n < 2; ++n) {
                acc[m][n + 2] = MFMA(af[m][0], bh[n][0], acc[m][n + 2], 0, 0, 0);
                acc[m][n + 2] = MFMA(af[m][1], bh[n][1], acc[m][n + 2], 0, 0, 0);
            }
        __builtin_amdgcn_s_setprio(0);
        FENCE(); __builtin_amdgcn_s_barrier(); FENCE();

        // ===== phase 3: read A-Mhi; stage B-Nhi(kt+2); MFMA m4-7 x n2-3 =====
        #pragma unroll
        for (int m = 0; m < 4; ++m) {
            af[m][0] = *(const bf16v8*)(aRd + bo + (m + 4) * 2048 + kx0);
            af[m][1] = *(const bf16v8*)(aRd + bo + (m + 4) * 2048 + kx1);
        }
        STAGE_B(bo, 1, kk2);
        FENCE(); __builtin_amdgcn_s_barrier(); FENCE();
        __builtin_amdgcn_s_setprio(1);
        #pragma unroll
        for (int m = 0; m < 4; ++m)
            #pragma unroll
            for (int n = 0; n < 2; ++n) {
                acc[m + 4][n + 2] = MFMA(af[m][0], bh[n][0], acc[m + 4][n + 2], 0, 0, 0);
                acc[m + 4][n + 2] = MFMA(af[m][1], bh[n][1], acc[m + 4][n + 2], 0, 0, 0);
            }
        __builtin_amdgcn_s_setprio(0);
        FENCE(); __builtin_amdgcn_s_barrier(); FENCE();

        // ===== phase 4: stage A-Mlo(kt+2); vmcnt(6); MFMA m4-7 x n0-1 =====
        STAGE_A(bo, 0, kk2);
        asm volatile("s_waitcnt vmcnt(6)" ::: "memory");
        FENCE(); __builtin_amdgcn_s_barrier(); FENCE();
        __builtin_amdgcn_s_setprio(1);
        #pragma unroll
        for (int m = 0; m < 4; ++m)
            #pragma unroll
            for (int n = 0; n < 2; ++n) {
                acc[m + 4][n] = MFMA(af[m][0], bl[n][0], acc[m + 4][n], 0, 0, 0);
                acc[m + 4][n] = MFMA(af[m][1], bl[n][1], acc[m + 4][n], 0, 0, 0);
            }
        __builtin_amdgcn_s_setprio(0);
        FENCE(); __builtin_amdgcn_s_barrier(); FENCE();
    }

    // ---- LoRA extension: one zero-padded K=32 MFMA per fragment ----
    asm volatile("s_waitcnt vmcnt(0)" ::: "memory");
    __syncthreads();
    {
        const int r = tid >> 1;
        const int h = (tid & 1) * 8;
        bf16v8 zv;
        #pragma unroll
        for (int i = 0; i < 8; ++i) zv[i] = (__bf16)0.f;

        __bf16* tE = (__bf16*)smem;            // [256][40] bf16 (pad 8)
        __bf16* LE = (__bf16*)(smem + 20480);  // [256][40]

        const float* tp = tpr + (size_t)(row0 + r) * 16 + h;
        float4 t0 = *(const float4*)tp;
        float4 t1 = *(const float4*)(tp + 4);
        bf16v8 tv;
        tv[0]=(__bf16)t0.x; tv[1]=(__bf16)t0.y; tv[2]=(__bf16)t0.z; tv[3]=(__bf16)t0.w;
        tv[4]=(__bf16)t1.x; tv[5]=(__bf16)t1.y; tv[6]=(__bf16)t1.z; tv[7]=(__bf16)t1.w;
        *(bf16v8*)(tE + r * 40 + h) = tv;
        *(bf16v8*)(tE + r * 40 + 16 + h) = zv;

        const int bb = row0 >> 11;
        const float* lp = lleft + ((size_t)bb * 16 + h) * 2048 + col0 + r;
        bf16v8 lv;
        #pragma unroll
        for (int i = 0; i < 8; ++i) lv[i] = (__bf16)lp[(size_t)i * 2048];
        *(bf16v8*)(LE + r * 40 + h) = lv;
        *(bf16v8*)(LE + r * 40 + 16 + h) = zv;
    }
    __syncthreads();
    {
        const __bf16* tE = (const __bf16*)smem;
        const __bf16* LE = (const __bf16*)(smem + 20480);
        const int ko = (lane >> 4) * 8;
        bf16v8 bE[4];
        #pragma unroll
        for (int n = 0; n < 4; ++n)
            bE[n] = *(const bf16v8*)(LE + (wn * 64 + n * 16 + fr) * 40 + ko);
        #pragma unroll
        for (int m = 0; m < 8; ++m) {
            bf16v8 aE = *(const bf16v8*)(tE + (wm * 128 + m * 16 + fr) * 40 + ko);
            #pragma unroll
            for (int n = 0; n < 4; ++n)
                acc[m][n] = MFMA(aE, bE[n], acc[m][n], 0, 0, 0);
        }
    }

    // ---- writeout + bias ----
    #pragma unroll
    for (int n = 0; n < 4; ++n) {
        const int gc = col0 + wn * 64 + n * 16 + fr;
        const float bv = bias[gc];
        #pragma unroll
        for (int m = 0; m < 8; ++m) {
            #pragma unroll
            for (int j = 0; j < 4; ++j) {
                const int gr = row0 + wm * 128 + m * 16 + (lane >> 4) * 4 + j;
                out[(size_t)gr * 2048 + gc] = acc[m][n][j] + bv;
            }
        }
    }
#undef STAGE_A
#undef STAGE_B
}

// ---------------------------------------------------------------------------
extern "C" void kernel_launch(void* const* d_in, const int* in_sizes, int n_in,
                              void* d_out, int out_size, void* d_ws, size_t ws_size,
                              hipStream_t stream) {
    const float* inp  = (const float*)d_in[0];   // [4,2048,2048]
    const float* wgt  = (const float*)d_in[1];   // [2048,2048]
    const float* bias = (const float*)d_in[2];   // [2048]
    const float* lrt  = (const float*)d_in[3];   // [4,2048,16]
    const float* llf  = (const float*)d_in[4];   // [4,16,2048]
    float* out = (float*)d_out;                  // [4,2048,2048]

    char* ws = (char*)d_ws;
    __bf16* abf  = (__bf16*)ws;                    // 33,554,432 B
    __bf16* wbf  = (__bf16*)(ws + 33554432);       //  8,388,608 B
    float*  tbuf = (float*)(ws + 41943040);        //    524,288 B
    float*  gprt = (float*)(ws + 42467328);        //     32,768 B
    float*  lrT  = (float*)(ws + 42500096);        //    524,288 B

    transpose_lr_kernel<<<dim3(8, 4), 256, 0, stream>>>(lrt, lrT);
    prep_kernel<<<4128, 256, 0, stream>>>(inp, wgt, lrT, llf, abf, wbf, tbuf, gprt);
    norm_kernel<<<32, 256, 0, stream>>>(gprt, tbuf);
    gemm_ep_kernel<<<dim3(256), 512, 0, stream>>>(abf, wbf, bias, tbuf, llf, out);
}

// Round 6
// 111.826 us; speedup vs baseline: 1.6143x; 1.0069x over previous
//
#include <hip/hip_runtime.h>
#include <hip/hip_bf16.h>

// Shapes fixed by reference: B=4, S=2048, D=K=2048, R=N=2048, LR=16, M=B*S=8192
#define SCALE_V 1.0f

typedef __bf16 bf16v8 __attribute__((ext_vector_type(8)));
typedef float f32v4 __attribute__((ext_vector_type(4)));

typedef const __attribute__((address_space(1))) void* gas_t;
typedef __attribute__((address_space(3))) void* las_t;
#define ASYNC_COPY16(g, l) \
    __builtin_amdgcn_global_load_lds((gas_t)(g), (las_t)(l), 16, 0, 0)
#define FENCE() asm volatile("" ::: "memory")
#define MFMA __builtin_amdgcn_mfma_f32_16x16x32_bf16

// ---------------------------------------------------------------------------
// transpose_lr: lrT[b][k][d] = lright[b][d][k]   (512 KB total, LDS-bounced)
// ---------------------------------------------------------------------------
__global__ __launch_bounds__(256) void transpose_lr_kernel(
    const float* __restrict__ lright, float* __restrict__ lrT) {
    __shared__ float tile[16][273];
    const int b = blockIdx.y;
    const int d0 = blockIdx.x * 256;
    const int t = threadIdx.x;
    const float* src = lright + (size_t)b * 32768 + (size_t)d0 * 16;
    #pragma unroll
    for (int j = 0; j < 16; ++j) {
        tile[t & 15][j * 16 + (t >> 4)] = src[j * 256 + t];
    }
    __syncthreads();
    const int k = t >> 4, dcol = t & 15;
    float* dst = lrT + (size_t)b * 32768 + (size_t)k * 2048 + d0;
    #pragma unroll
    for (int j = 0; j < 16; ++j) {
        dst[dcol + j * 16] = tile[k][dcol + j * 16];
    }
}

// ---------------------------------------------------------------------------
// prep: fused  [blocks 0..2047]  lora_t : abf = bf16(input), t = input@lora_right
//              [blocks 2048..4095] convert_w : wbf = bf16(weight)
//              [blocks 4096..4127] gram partials : G[b] = L L^T
// ---------------------------------------------------------------------------
__global__ __launch_bounds__(256) void prep_kernel(
    const float* __restrict__ inp, const float* __restrict__ wgt,
    const float* __restrict__ lrT, const float* __restrict__ lleft,
    __bf16* __restrict__ abf, __bf16* __restrict__ wbf,
    float* __restrict__ tout, float* __restrict__ gpart) {
    __shared__ float sm[256];
    const int bid = blockIdx.x;
    const int tid = threadIdx.x;

    if (bid < 2048) {
        const int row0 = bid * 4;
        const int b = row0 >> 11;
        const float* lt = lrT + (size_t)b * 32768;   // [16][2048]

        float x[4][8];
        #pragma unroll
        for (int rr = 0; rr < 4; ++rr) {
            const float* p = inp + (size_t)(row0 + rr) * 2048 + tid * 8;
            float4 a0 = *(const float4*)p;
            float4 a1 = *(const float4*)(p + 4);
            x[rr][0] = a0.x; x[rr][1] = a0.y; x[rr][2] = a0.z; x[rr][3] = a0.w;
            x[rr][4] = a1.x; x[rr][5] = a1.y; x[rr][6] = a1.z; x[rr][7] = a1.w;
            bf16v8 v;
            #pragma unroll
            for (int i = 0; i < 8; ++i) v[i] = (__bf16)x[rr][i];
            *(bf16v8*)(abf + (size_t)(row0 + rr) * 2048 + tid * 8) = v;
        }

        float v[64];
        #pragma unroll
        for (int k = 0; k < 16; ++k) {
            const float* lp = lt + (size_t)k * 2048 + tid * 8;
            float4 l0 = *(const float4*)lp;
            float4 l1 = *(const float4*)(lp + 4);
            float lv[8] = {l0.x, l0.y, l0.z, l0.w, l1.x, l1.y, l1.z, l1.w};
            #pragma unroll
            for (int rr = 0; rr < 4; ++rr) {
                float s = 0.f;
                #pragma unroll
                for (int i = 0; i < 8; ++i) s += x[rr][i] * lv[i];
                v[rr * 16 + k] = s;
            }
        }

        // in-register butterfly reduce-scatter (verified R4/R5)
        const int lane = tid & 63;
        const int w = tid >> 6;
        #pragma unroll
        for (int s = 1, cnt = 64; s < 64; s <<= 1, cnt >>= 1) {
            const int half = cnt >> 1;
            const bool up = (lane & s) != 0;
            #pragma unroll
            for (int i = 0; i < 32; ++i) {
                if (i < half) {
                    float keep = up ? v[i + half] : v[i];
                    float give = up ? v[i] : v[i + half];
                    v[i] = keep + __shfl_xor(give, s, 64);
                }
            }
        }
        const int rev = ((lane & 1) << 5) | ((lane & 2) << 3) | ((lane & 4) << 1) |
                        ((lane & 8) >> 1) | ((lane & 16) >> 3) | ((lane & 32) >> 5);
        sm[w * 64 + rev] = v[0];
        __syncthreads();
        if (tid < 64) {
            tout[(size_t)row0 * 16 + tid] =
                sm[tid] + sm[64 + tid] + sm[128 + tid] + sm[192 + tid];
        }
    } else if (bid < 4096) {
        const int i = ((bid - 2048) * 256 + tid) * 8;
        float4 x0 = *(const float4*)(wgt + i);
        float4 x1 = *(const float4*)(wgt + i + 4);
        bf16v8 v;
        v[0] = (__bf16)x0.x; v[1] = (__bf16)x0.y; v[2] = (__bf16)x0.z; v[3] = (__bf16)x0.w;
        v[4] = (__bf16)x1.x; v[5] = (__bf16)x1.y; v[6] = (__bf16)x1.z; v[7] = (__bf16)x1.w;
        *(bf16v8*)(wbf + i) = v;
    } else {
        const int g = bid - 4096;
        const int b = g >> 3, c = g & 7;
        const int k = tid >> 4, j = tid & 15;
        const float* pk = lleft + ((size_t)b * 16 + k) * 2048 + c * 256;
        const float* pj = lleft + ((size_t)b * 16 + j) * 2048 + c * 256;
        float s = 0.f;
        #pragma unroll 4
        for (int r = 0; r < 256; r += 4) {
            float4 a = *(const float4*)(pk + r);
            float4 d = *(const float4*)(pj + r);
            s += a.x * d.x + a.y * d.y + a.z * d.z + a.w * d.w;
        }
        gpart[((size_t)b * 8 + c) * 256 + tid] = s;
    }
}

// ---------------------------------------------------------------------------
// norm: fold Gram partials; t' = SCALE * t * rsqrt(t^T G t)  (in place)
// ---------------------------------------------------------------------------
__global__ __launch_bounds__(256) void norm_kernel(
    const float* __restrict__ gpart, float* __restrict__ t) {
    __shared__ float gs[256];
    const int tid = threadIdx.x;
    const int tok0 = blockIdx.x * 256;
    const int b = tok0 >> 11;
    float g = 0.f;
    #pragma unroll
    for (int c = 0; c < 8; ++c) g += gpart[((size_t)b * 8 + c) * 256 + tid];
    gs[tid] = g;
    __syncthreads();

    float* tp = t + (size_t)(tok0 + tid) * 16;
    float tv[16];
    {
        float4 a0 = *(const float4*)(tp);
        float4 a1 = *(const float4*)(tp + 4);
        float4 a2 = *(const float4*)(tp + 8);
        float4 a3 = *(const float4*)(tp + 12);
        tv[0]=a0.x; tv[1]=a0.y; tv[2]=a0.z; tv[3]=a0.w;
        tv[4]=a1.x; tv[5]=a1.y; tv[6]=a1.z; tv[7]=a1.w;
        tv[8]=a2.x; tv[9]=a2.y; tv[10]=a2.z; tv[11]=a2.w;
        tv[12]=a3.x; tv[13]=a3.y; tv[14]=a3.z; tv[15]=a3.w;
    }
    float q = 0.f;
    #pragma unroll
    for (int k = 0; k < 16; ++k) {
        float s = 0.f;
        #pragma unroll
        for (int j = 0; j < 16; ++j) s += gs[k * 16 + j] * tv[j];
        q += tv[k] * s;
    }
    const float r = SCALE_V * rsqrtf(q);
    float4 o;
    o.x = tv[0]*r;  o.y = tv[1]*r;  o.z = tv[2]*r;  o.w = tv[3]*r;  *(float4*)(tp)      = o;
    o.x = tv[4]*r;  o.y = tv[5]*r;  o.z = tv[6]*r;  o.w = tv[7]*r;  *(float4*)(tp + 4)  = o;
    o.x = tv[8]*r;  o.y = tv[9]*r;  o.z = tv[10]*r; o.w = tv[11]*r; *(float4*)(tp + 8)  = o;
    o.x = tv[12]*r; o.y = tv[13]*r; o.z = tv[14]*r; o.w = tv[15]*r; *(float4*)(tp + 12) = o;
}

// ---------------------------------------------------------------------------
// gemm: 256x256 tile, BK=64, 8 waves (2Mx4N), 4 phases/K-tile x 2 dbuf.
// R6 changes: (1) chunked XCD swizzle: each XCD owns 4 tile_m x 8 tile_n
//             (2) two-tier counted vmcnt: vmcnt(10) @p2, vmcnt(8) @p4
// Region-pipeline stage/read ledger (steady state, iteration kt):
//   p1 stages Ahi(kt+1); p2 stages Blo(kt+2); p3 Bhi(kt+2); p4 Alo(kt+2)
//   p1 reads Alo(kt)[p4,kt-2] + Blo(kt)[p2,kt-2]; p2 reads Bhi(kt)[p3,kt-2];
//   p3 reads Ahi(kt)[p1,kt-1]; p4 reads regs only.
//   vmcnt(8)@p4 completes loads through p4(kt-1) -> covers p1/p2 reads of kt+1.
//   vmcnt(10)@p2 completes loads through p1(kt-1) -> covers p3 read of kt.
// ---------------------------------------------------------------------------
__global__ __launch_bounds__(512, 2) void gemm_ep_kernel(
    const __bf16* __restrict__ abf, const __bf16* __restrict__ wbf,
    const float* __restrict__ bias, const float* __restrict__ tpr,
    const float* __restrict__ lleft, float* __restrict__ out) {
    __shared__ __attribute__((aligned(16))) char smem[131072];  // As[2][256][64] | Bs[2][256][64] bf16

    const int tid  = threadIdx.x;
    const int w    = tid >> 6;           // wave 0..7
    const int lane = tid & 63;
    const int l3   = lane >> 3, l7 = lane & 7;
    const int wm   = w >> 2;             // 0..1 (M half)
    const int wn   = w & 3;              // 0..3 (N quarter)
    const int fr   = lane & 15;

    // chunked XCD swizzle: xcd = bid&7 owns tile_m in [4*xcd, 4*xcd+4), all tile_n
    const int xcd   = blockIdx.x & 7;
    const int local = blockIdx.x >> 3;          // 0..31
    const int tile_n = local & 7;
    const int tile_m = (xcd << 2) | (local >> 3);
    const int row0 = tile_m * 256;
    const int col0 = tile_n * 256;

    // staging: pre-swizzled global source column
    const int cswz = ((l7 ^ l3) * 8);                       // elements
    const size_t aG0 = (size_t)(row0 + 8 * w + l3) * 2048 + cswz;
    const int bCh = 64 * (w >> 2) + 8 * (w & 3);
    const size_t bG0 = (size_t)(col0 + bCh + l3) * 2048 + cswz;
    char* const aDst = smem + 8 * w * 128 + lane * 16;
    char* const bDst = smem + 65536 + bCh * 128 + lane * 16;

#define STAGE_A(BUFOFF, S, KKEL)                                                         \
    do {                                                                                 \
        ASYNC_COPY16(abf + aG0 + (size_t)((S)*64) * 2048 + (KKEL),  aDst + (BUFOFF) + (S)*8192);          \
        ASYNC_COPY16(abf + aG0 + (size_t)((S)*64 + 128) * 2048 + (KKEL), aDst + (BUFOFF) + (S)*8192 + 16384); \
    } while (0)
#define STAGE_B(BUFOFF, S, KKEL)                                                         \
    do {                                                                                 \
        ASYNC_COPY16(wbf + bG0 + (size_t)((S)*32) * 2048 + (KKEL),  bDst + (BUFOFF) + (S)*4096);          \
        ASYNC_COPY16(wbf + bG0 + (size_t)((S)*32 + 128) * 2048 + (KKEL), bDst + (BUFOFF) + (S)*4096 + 16384); \
    } while (0)

    // fragment read bases (byte addrs), swizzled k-offset per lane
    const int kx0 = (((lane >> 4) * 16) ^ (l7 << 4));
    const int kx1 = ((64 + (lane >> 4) * 16) ^ (l7 << 4));
    const char* const aRd = smem + (wm * 128 + fr) * 128;
    const char* const bRd = smem + 65536 + (wn * 64 + fr) * 128;

    f32v4 acc[8][4];
    #pragma unroll
    for (int m = 0; m < 8; ++m)
        #pragma unroll
        for (int n = 0; n < 4; ++n) {
            acc[m][n][0] = 0.f; acc[m][n][1] = 0.f;
            acc[m][n][2] = 0.f; acc[m][n][3] = 0.f;
        }

    // ---- prologue: stage kt0 fully + kt1 {B-lo, B-hi, A-lo} ----
    STAGE_A(0, 0, 0);      // A-Mlo(0)
    STAGE_B(0, 0, 0);      // B-Nlo(0)
    STAGE_B(0, 1, 0);      // B-Nhi(0)
    STAGE_A(0, 1, 0);      // A-Mhi(0)
    STAGE_B(32768, 0, 64); // B-Nlo(1)
    STAGE_B(32768, 1, 64); // B-Nhi(1)
    STAGE_A(32768, 0, 64); // A-Mlo(1)
    asm volatile("s_waitcnt vmcnt(8)" ::: "memory");  // drains Alo0,Blo0,Bhi0
    FENCE(); __builtin_amdgcn_s_barrier(); FENCE();

    for (int kt = 0; kt < 32; ++kt) {
        const int bo = (kt & 1) * 32768;
        const int bn = bo ^ 32768;
        const size_t kk1 = (size_t)((kt + 1) & 31) * 64;
        const size_t kk2 = (size_t)((kt + 2) & 31) * 64;
        bf16v8 af[4][2], bl[2][2], bh[2][2];

        // ===== phase 1: read A-Mlo + B-Nlo; stage A-Mhi(kt+1); MFMA m0-3 x n0-1 =====
        #pragma unroll
        for (int m = 0; m < 4; ++m) {
            af[m][0] = *(const bf16v8*)(aRd + bo + m * 2048 + kx0);
            af[m][1] = *(const bf16v8*)(aRd + bo + m * 2048 + kx1);
        }
        #pragma unroll
        for (int n = 0; n < 2; ++n) {
            bl[n][0] = *(const bf16v8*)(bRd + bo + n * 2048 + kx0);
            bl[n][1] = *(const bf16v8*)(bRd + bo + n * 2048 + kx1);
        }
        STAGE_A(bn, 1, kk1);
        FENCE(); __builtin_amdgcn_s_barrier(); FENCE();
        __builtin_amdgcn_s_setprio(1);
        #pragma unroll
        for (int m = 0; m < 4; ++m)
            #pragma unroll
            for (int n = 0; n < 2; ++n) {
                acc[m][n] = MFMA(af[m][0], bl[n][0], acc[m][n], 0, 0, 0);
                acc[m][n] = MFMA(af[m][1], bl[n][1], acc[m][n], 0, 0, 0);
            }
        __builtin_amdgcn_s_setprio(0);
        FENCE(); __builtin_amdgcn_s_barrier(); FENCE();

        // ===== phase 2: read B-Nhi; stage B-Nlo(kt+2); vmcnt(10); MFMA m0-3 x n2-3 =====
        #pragma unroll
        for (int n = 0; n < 2; ++n) {
            bh[n][0] = *(const bf16v8*)(bRd + bo + (n + 2) * 2048 + kx0);
            bh[n][1] = *(const bf16v8*)(bRd + bo + (n + 2) * 2048 + kx1);
        }
        STAGE_B(bo, 0, kk2);
        asm volatile("s_waitcnt vmcnt(10)" ::: "memory");  // completes Ahi(kt) for p3
        FENCE(); __builtin_amdgcn_s_barrier(); FENCE();
        __builtin_amdgcn_s_setprio(1);
        #pragma unroll
        for (int m = 0; m < 4; ++m)
            #pragma unroll
            for (int n = 0; n < 2; ++n) {
                acc[m][n + 2] = MFMA(af[m][0], bh[n][0], acc[m][n + 2], 0, 0, 0);
                acc[m][n + 2] = MFMA(af[m][1], bh[n][1], acc[m][n + 2], 0, 0, 0);
            }
        __builtin_amdgcn_s_setprio(0);
        FENCE(); __builtin_amdgcn_s_barrier(); FENCE();

        // ===== phase 3: read A-Mhi; stage B-Nhi(kt+2); MFMA m4-7 x n2-3 =====
        #pragma unroll
        for (int m = 0; m < 4; ++m) {
            af[m][0] = *(const bf16v8*)(aRd + bo + (m + 4) * 2048 + kx0);
            af[m][1] = *(const bf16v8*)(aRd + bo + (m + 4) * 2048 + kx1);
        }
        STAGE_B(bo, 1, kk2);
        FENCE(); __builtin_amdgcn_s_barrier(); FENCE();
        __builtin_amdgcn_s_setprio(1);
        #pragma unroll
        for (int m = 0; m < 4; ++m)
            #pragma unroll
            for (int n = 0; n < 2; ++n) {
                acc[m + 4][n + 2] = MFMA(af[m][0], bh[n][0], acc[m + 4][n + 2], 0, 0, 0);
                acc[m + 4][n + 2] = MFMA(af[m][1], bh[n][1], acc[m + 4][n + 2], 0, 0, 0);
            }
        __builtin_amdgcn_s_setprio(0);
        FENCE(); __builtin_amdgcn_s_barrier(); FENCE();

        // ===== phase 4: stage A-Mlo(kt+2); vmcnt(8); MFMA m4-7 x n0-1 =====
        STAGE_A(bo, 0, kk2);
        asm volatile("s_waitcnt vmcnt(8)" ::: "memory");  // completes Blo/Bhi/Alo(kt+1)
        FENCE(); __builtin_amdgcn_s_barrier(); FENCE();
        __builtin_amdgcn_s_setprio(1);
        #pragma unroll
        for (int m = 0; m < 4; ++m)
            #pragma unroll
            for (int n = 0; n < 2; ++n) {
                acc[m + 4][n] = MFMA(af[m][0], bl[n][0], acc[m + 4][n], 0, 0, 0);
                acc[m + 4][n] = MFMA(af[m][1], bl[n][1], acc[m + 4][n], 0, 0, 0);
            }
        __builtin_amdgcn_s_setprio(0);
        FENCE(); __builtin_amdgcn_s_barrier(); FENCE();
    }

    // ---- LoRA extension: one zero-padded K=32 MFMA per fragment ----
    asm volatile("s_waitcnt vmcnt(0)" ::: "memory");
    __syncthreads();
    {
        const int r = tid >> 1;
        const int h = (tid & 1) * 8;
        bf16v8 zv;
        #pragma unroll
        for (int i = 0; i < 8; ++i) zv[i] = (__bf16)0.f;

        __bf16* tE = (__bf16*)smem;            // [256][40] bf16 (pad 8)
        __bf16* LE = (__bf16*)(smem + 20480);  // [256][40]

        const float* tp = tpr + (size_t)(row0 + r) * 16 + h;
        float4 t0 = *(const float4*)tp;
        float4 t1 = *(const float4*)(tp + 4);
        bf16v8 tv;
        tv[0]=(__bf16)t0.x; tv[1]=(__bf16)t0.y; tv[2]=(__bf16)t0.z; tv[3]=(__bf16)t0.w;
        tv[4]=(__bf16)t1.x; tv[5]=(__bf16)t1.y; tv[6]=(__bf16)t1.z; tv[7]=(__bf16)t1.w;
        *(bf16v8*)(tE + r * 40 + h) = tv;
        *(bf16v8*)(tE + r * 40 + 16 + h) = zv;

        const int bb = row0 >> 11;
        const float* lp = lleft + ((size_t)bb * 16 + h) * 2048 + col0 + r;
        bf16v8 lv;
        #pragma unroll
        for (int i = 0; i < 8; ++i) lv[i] = (__bf16)lp[(size_t)i * 2048];
        *(bf16v8*)(LE + r * 40 + h) = lv;
        *(bf16v8*)(LE + r * 40 + 16 + h) = zv;
    }
    __syncthreads();
    {
        const __bf16* tE = (const __bf16*)smem;
        const __bf16* LE = (const __bf16*)(smem + 20480);
        const int ko = (lane >> 4) * 8;
        bf16v8 bE[4];
        #pragma unroll
        for (int n = 0; n < 4; ++n)
            bE[n] = *(const bf16v8*)(LE + (wn * 64 + n * 16 + fr) * 40 + ko);
        #pragma unroll
        for (int m = 0; m < 8; ++m) {
            bf16v8 aE = *(const bf16v8*)(tE + (wm * 128 + m * 16 + fr) * 40 + ko);
            #pragma unroll
            for (int n = 0; n < 4; ++n)
                acc[m][n] = MFMA(aE, bE[n], acc[m][n], 0, 0, 0);
        }
    }

    // ---- writeout + bias ----
    #pragma unroll
    for (int n = 0; n < 4; ++n) {
        const int gc = col0 + wn * 64 + n * 16 + fr;
        const float bv = bias[gc];
        #pragma unroll
        for (int m = 0; m < 8; ++m) {
            #pragma unroll
            for (int j = 0; j < 4; ++j) {
                const int gr = row0 + wm * 128 + m * 16 + (lane >> 4) * 4 + j;
                out[(size_t)gr * 2048 + gc] = acc[m][n][j] + bv;
            }
        }
    }
#undef STAGE_A
#undef STAGE_B
}

// ---------------------------------------------------------------------------
extern "C" void kernel_launch(void* const* d_in, const int* in_sizes, int n_in,
                              void* d_out, int out_size, void* d_ws, size_t ws_size,
                              hipStream_t stream) {
    const float* inp  = (const float*)d_in[0];   // [4,2048,2048]
    const float* wgt  = (const float*)d_in[1];   // [2048,2048]
    const float* bias = (const float*)d_in[2];   // [2048]
    const float* lrt  = (const float*)d_in[3];   // [4,2048,16]
    const float* llf  = (const float*)d_in[4];   // [4,16,2048]
    float* out = (float*)d_out;                  // [4,2048,2048]

    char* ws = (char*)d_ws;
    __bf16* abf  = (__bf16*)ws;                    // 33,554,432 B
    __bf16* wbf  = (__bf16*)(ws + 33554432);       //  8,388,608 B
    float*  tbuf = (float*)(ws + 41943040);        //    524,288 B
    float*  gprt = (float*)(ws + 42467328);        //     32,768 B
    float*  lrT  = (float*)(ws + 42500096);        //    524,288 B

    transpose_lr_kernel<<<dim3(8, 4), 256, 0, stream>>>(lrt, lrT);
    prep_kernel<<<4128, 256, 0, stream>>>(inp, wgt, lrT, llf, abf, wbf, tbuf, gprt);
    norm_kernel<<<32, 256, 0, stream>>>(gprt, tbuf);
    gemm_ep_kernel<<<dim3(256), 512, 0, stream>>>(abf, wbf, bias, tbuf, llf, out);
}